// Round 10
// baseline (471.528 us; speedup 1.0000x reference)
//
#include <hip/hip_runtime.h>
#include <math.h>

#define B_  2
#define T_  2048
#define C_  1024
#define H_  16
#define S_  16
#define HD_ 64
#define NCH 64
#define CHL 32   /* T_/NCH */

typedef short  short8  __attribute__((ext_vector_type(8)));
typedef unsigned short ushort8 __attribute__((ext_vector_type(8)));
typedef unsigned short ushort4v __attribute__((ext_vector_type(4)));
typedef float  f32x4   __attribute__((ext_vector_type(4)));

__device__ __forceinline__ float softplus_f(float v) {
    return fmaxf(v, 0.f) + log1pf(__expf(-fabsf(v)));
}

__device__ __forceinline__ unsigned short f2bf(float x) {
    unsigned u = __float_as_uint(x);
    u += 0x7fffu + ((u >> 16) & 1u);
    return (unsigned short)(u >> 16);
}

// async global -> LDS, 16B per lane. LDS dest = wave-uniform base + lane*16.
__device__ __forceinline__ void gload16(const unsigned short* g,
                                        unsigned short* l)
{
    __builtin_amdgcn_global_load_lds(
        (const __attribute__((address_space(1))) unsigned int*)g,
        (__attribute__((address_space(3))) unsigned int*)l, 16, 0, 0);
}

// ---------------------------------------------------------------------------
// cast fp32 -> bf16 (vectorized), n4 = n/4
// ---------------------------------------------------------------------------
__global__ __launch_bounds__(256) void cast_bf16(const float* __restrict__ in,
                                                 unsigned short* __restrict__ out,
                                                 int n4)
{
    int i = blockIdx.x * 256 + threadIdx.x;
    if (i >= n4) return;
    float4 v = ((const float4*)in)[i];
    ushort4v o = {f2bf(v.x), f2bf(v.y), f2bf(v.z), f2bf(v.w)};
    ((ushort4v*)out)[i] = o;
}

// ---------------------------------------------------------------------------
// transpose-cast: W (1024 x 1024 fp32) -> WT (1024 x 1024 bf16, transposed)
// ---------------------------------------------------------------------------
__device__ __forceinline__ void wtrans_body(const float* __restrict__ W,
                                            unsigned short* __restrict__ WT,
                                            int bx, int by, int tid)
{
    __shared__ float t[32][33];
    const int n0 = bx * 32, k0 = by * 32;
    const int tx = tid & 31, ty = tid >> 5;
#pragma unroll
    for (int p = 0; p < 4; ++p)
        t[ty + p * 8][tx] = W[(size_t)(k0 + ty + p * 8) * C_ + n0 + tx];
    __syncthreads();
#pragma unroll
    for (int p = 0; p < 4; ++p)
        WT[(size_t)(n0 + ty + p * 8) * C_ + k0 + tx] = f2bf(t[tx][ty + p * 8]);
}

__global__ __launch_bounds__(256) void wtrans(const float* __restrict__ W,
                                              unsigned short* __restrict__ WT)
{
    wtrans_body(W, WT, blockIdx.x, blockIdx.y, threadIdx.x);
}

// z: 0 Wx->Astack, 1 Wd->Astack+1024 rows, 2 Wq->Wqkv, 3 Wk->+1024, 4 Wv->+2048
__global__ __launch_bounds__(256) void wtrans_multi(
    const float* __restrict__ Wx, const float* __restrict__ Wd,
    const float* __restrict__ Wq, const float* __restrict__ Wk,
    const float* __restrict__ Wv,
    unsigned short* __restrict__ Astack, unsigned short* __restrict__ Wqkv)
{
    const float* src;
    unsigned short* dst;
    switch (blockIdx.z) {
        case 0: src = Wx; dst = Astack; break;
        case 1: src = Wd; dst = Astack + (size_t)1024 * 1024; break;
        case 2: src = Wq; dst = Wqkv; break;
        case 3: src = Wk; dst = Wqkv + (size_t)1024 * 1024; break;
        default: src = Wv; dst = Wqkv + (size_t)2048 * 1024; break;
    }
    wtrans_body(src, dst, blockIdx.x, blockIdx.y, threadIdx.x);
}

// ---------------------------------------------------------------------------
// misc prep: WB/WC transposed into Astack rows 2048..2079 + stacked biases
// ---------------------------------------------------------------------------
__global__ __launch_bounds__(256) void prep_misc(
    const float* __restrict__ WB, const float* __restrict__ WC,
    const float* __restrict__ bx, const float* __restrict__ bd,
    const float* __restrict__ bq, const float* __restrict__ bk,
    const float* __restrict__ bv,
    unsigned short* __restrict__ Astack, float* __restrict__ biasPD,
    float* __restrict__ biasQKV)
{
    int gid = blockIdx.x * 256 + threadIdx.x;
    if (gid < 32768) {
        int w = gid >> 14, rem = gid & 16383;
        int s = rem >> 10, k = rem & 1023;
        const float* src = w ? WC : WB;
        Astack[(size_t)(2048 + w * 16 + s) * 1024 + k] = f2bf(src[k * 16 + s]);
    } else {
        int id = gid - 32768;
        if (id < 2176) {
            biasPD[id] = id < 1024 ? bx[id] : (id < 2048 ? bd[id - 1024] : 0.f);
        } else {
            int id2 = id - 2176;
            if (id2 < 3072)
                biasQKV[id2] = id2 < 1024 ? bq[id2]
                             : (id2 < 2048 ? bk[id2 - 1024] : bv[id2 - 2048]);
        }
    }
}

// ---------------------------------------------------------------------------
// bf16 MFMA GEMM: acc = A(M x K) @ B(N x K)^T, both lda-strided K-major bf16.
// 128x128 tile, BK=32, 256 threads = 4 waves (2x2 of 64x64).
// R2-verified 4-buffer counted-vmcnt pipeline.
// K must be a multiple of 128 (1024 here).
// mode 0: direct fp32 out with bias (Wo projection -> d_out)
// ---------------------------------------------------------------------------
__global__ __launch_bounds__(256) void gemm_mfma(
    const unsigned short* __restrict__ A, const unsigned short* __restrict__ Bm,
    const float* __restrict__ bias,
    void* __restrict__ outv,
    int M, int N, int K, int lda)
{
    __shared__ __align__(16) unsigned short As[4][4096];
    __shared__ __align__(16) unsigned short Bs[4][4096];

    const int tid = threadIdx.x;
    const int w = tid >> 6, lane = tid & 63;
    const int lq = lane & 15, lg = lane >> 4;
    const int wm = w >> 1, wn = w & 1;
    const int mBase = blockIdx.y * 128, nBase = blockIdx.x * 128;

    const int c0 = tid, c1 = tid + 256;
    const int rA0 = ((c0 >> 6) << 4) + (c0 & 15), kO0 = ((c0 >> 4) & 3) << 3;
    const int rA1 = ((c1 >> 6) << 4) + (c1 & 15), kO1 = ((c1 >> 4) & 3) << 3;

    const int wL0 = w * 512;
    const int wL1 = 2048 + w * 512;

    f32x4 acc[4][4];
#pragma unroll
    for (int i = 0; i < 4; ++i)
#pragma unroll
        for (int j = 0; j < 4; ++j) acc[i][j] = (f32x4){0.f, 0.f, 0.f, 0.f};

    const unsigned short* ga0 = A  + (size_t)(mBase + rA0) * lda + kO0;
    const unsigned short* ga1 = A  + (size_t)(mBase + rA1) * lda + kO1;
    const unsigned short* gb0 = Bm + (size_t)(nBase + rA0) * lda + kO0;
    const unsigned short* gb1 = Bm + (size_t)(nBase + rA1) * lda + kO1;

    #define STAGE(bufv, k0v)                               \
        do {                                               \
            gload16(ga0 + (k0v), &As[bufv][wL0]);          \
            gload16(ga1 + (k0v), &As[bufv][wL1]);          \
            gload16(gb0 + (k0v), &Bs[bufv][wL0]);          \
            gload16(gb1 + (k0v), &Bs[bufv][wL1]);          \
        } while (0)
    #define COMPUTE(bufv)                                                       \
        do {                                                                    \
            short8 a[4], b[4];                                                  \
            _Pragma("unroll")                                                   \
            for (int i = 0; i < 4; ++i)                                         \
                a[i] = *(const short8*)&As[bufv][((wm * 4 + i) * 64 + lg * 16 + lq) * 8]; \
            _Pragma("unroll")                                                   \
            for (int j = 0; j < 4; ++j)                                         \
                b[j] = *(const short8*)&Bs[bufv][((wn * 4 + j) * 64 + lg * 16 + lq) * 8]; \
            _Pragma("unroll")                                                   \
            for (int i = 0; i < 4; ++i)                                         \
                _Pragma("unroll")                                               \
                for (int j = 0; j < 4; ++j)                                     \
                    acc[i][j] = __builtin_amdgcn_mfma_f32_16x16x32_bf16(        \
                        a[i], b[j], acc[i][j], 0, 0, 0);                        \
        } while (0)
    #define WAITV4() asm volatile("s_waitcnt vmcnt(4)" ::: "memory")
    #define WAITV0() asm volatile("s_waitcnt vmcnt(0)" ::: "memory")
    #define LGKM0()  asm volatile("s_waitcnt lgkmcnt(0)" ::: "memory")
    #define STEP(cbuf, kt)                                          \
        do {                                                        \
            if ((kt) + 32 < K) WAITV4(); else WAITV0();             \
            LGKM0();                                                \
            __builtin_amdgcn_s_barrier();                           \
            if ((kt) + 64 < K) STAGE(((cbuf) + 2) & 3, (kt) + 64);  \
            COMPUTE(cbuf);                                          \
        } while (0)

    STAGE(0, 0);
    STAGE(1, 32);

    for (int k0 = 0; k0 < K; k0 += 128) {
        STEP(0, k0);
        STEP(1, k0 + 32);
        STEP(2, k0 + 64);
        STEP(3, k0 + 96);
    }
    #undef STAGE
    #undef COMPUTE
    #undef WAITV4
    #undef WAITV0
    #undef LGKM0
    #undef STEP

    // direct fp32 output with bias over N columns (Wo projection)
    float* O = (float*)outv;
#pragma unroll
    for (int j = 0; j < 4; ++j) {
        int Cg = nBase + wn * 64 + j * 16 + lq;
        float bb = bias[Cg];
#pragma unroll
        for (int i = 0; i < 4; ++i) {
            int Rb = mBase + wm * 64 + i * 16 + lg * 4;
#pragma unroll
            for (int r = 0; r < 4; ++r)
                O[(size_t)(Rb + r) * N + Cg] = acc[i][j][r] + bb;
        }
    }
}

// ---------------------------------------------------------------------------
// projT hybrid GEMM: BM=128, BN=256, BK=64, 512 thr = 8 waves (2M x 4N).
// Counted-vmcnt 2-phase-per-K-tile schedule, 272 blocks. (R8-verified.)
// ---------------------------------------------------------------------------
__global__ __launch_bounds__(512, 2) void gemm_projT(
    const unsigned short* __restrict__ A, const unsigned short* __restrict__ Bm,
    const float* __restrict__ bias,
    float* __restrict__ xbaseT, float* __restrict__ deltaT,
    float* __restrict__ BmT, float* __restrict__ CmT,
    int K, int lda)
{
    __shared__ __align__(16) unsigned short AS[2][2][4096];   // 128 x 32
    __shared__ __align__(16) unsigned short BS[2][2][8192];   // 256 x 32

    const int tid = threadIdx.x;              // 0..511
    const int w = tid >> 6, lane = tid & 63;
    const int lq = lane & 15, lg = lane >> 4;
    const int wm = w >> 2, wn = w & 3;        // 2M x 4N wave grid
    const int mBase = blockIdx.y * 128, nBase = blockIdx.x * 256;

    const int rA = ((tid >> 6) << 4) | (tid & 15);
    const int kA = ((tid >> 4) & 3) << 3;
    const unsigned short* gA = A + (size_t)(mBase + rA) * lda + kA;
    const int eA = tid * 8;
    const int c0 = tid, c1 = tid + 512;
    const int rB0 = ((c0 >> 6) << 4) | (c0 & 15), kB0 = ((c0 >> 4) & 3) << 3;
    const int rB1 = ((c1 >> 6) << 4) | (c1 & 15), kB1 = ((c1 >> 4) & 3) << 3;
    const unsigned short* gB0 = Bm + (size_t)(nBase + rB0) * lda + kB0;
    const unsigned short* gB1 = Bm + (size_t)(nBase + rB1) * lda + kB1;

    f32x4 acc[4][4];
#pragma unroll
    for (int i = 0; i < 4; ++i)
#pragma unroll
        for (int j = 0; j < 4; ++j) acc[i][j] = (f32x4){0.f, 0.f, 0.f, 0.f};

    #define STG(buf_, half_, kb_)                                             \
        do {                                                                  \
            gload16(gA  + (kb_) + (half_) * 32, &AS[buf_][half_][eA]);        \
            gload16(gB0 + (kb_) + (half_) * 32, &BS[buf_][half_][c0 * 8]);    \
            gload16(gB1 + (kb_) + (half_) * 32, &BS[buf_][half_][c1 * 8]);    \
        } while (0)
    #define WAITV6() asm volatile("s_waitcnt vmcnt(6)" ::: "memory")
    #define WAITV3() asm volatile("s_waitcnt vmcnt(3)" ::: "memory")
    #define WAITV0() asm volatile("s_waitcnt vmcnt(0)" ::: "memory")

    #define PHASE(buf_, half_, STAGE_STMT, GATE_STMT)                         \
        do {                                                                  \
            short8 a_[4], b_[4];                                              \
            _Pragma("unroll")                                                 \
            for (int i = 0; i < 4; ++i)                                       \
                a_[i] = *(const short8*)&AS[buf_][half_]                      \
                    [((wm * 4 + i) * 64 + lg * 16 + lq) * 8];                 \
            _Pragma("unroll")                                                 \
            for (int j = 0; j < 4; ++j)                                       \
                b_[j] = *(const short8*)&BS[buf_][half_]                      \
                    [((wn * 4 + j) * 64 + lg * 16 + lq) * 8];                 \
            STAGE_STMT;                                                       \
            __builtin_amdgcn_s_barrier();                                     \
            asm volatile("s_waitcnt lgkmcnt(0)" ::: "memory");                \
            __builtin_amdgcn_s_setprio(1);                                    \
            _Pragma("unroll")                                                 \
            for (int i = 0; i < 4; ++i)                                       \
                _Pragma("unroll")                                             \
                for (int j = 0; j < 4; ++j)                                   \
                    acc[i][j] = __builtin_amdgcn_mfma_f32_16x16x32_bf16(      \
                        a_[i], b_[j], acc[i][j], 0, 0, 0);                    \
            __builtin_amdgcn_s_setprio(0);                                    \
            GATE_STMT;                                                        \
            __builtin_amdgcn_s_barrier();                                     \
        } while (0)

    STG(0, 0, 0);
    STG(0, 1, 0);
    STG(1, 0, 64);
    WAITV6();
    __builtin_amdgcn_s_barrier();

    const int NT = K >> 6;                    // 16
    for (int kt = 0; kt < NT; ++kt) {
        const int buf = kt & 1, nbuf = buf ^ 1;
        const int kb1 = (kt + 1) << 6, kb2 = (kt + 2) << 6;
        PHASE(buf, 0, { if (kt + 1 < NT) STG(nbuf, 1, kb1); },
              { if (kt < NT - 1) WAITV6(); else WAITV3(); });
        PHASE(buf, 1, { if (kt + 2 < NT) STG(buf, 0, kb2); },
              { if (kt < NT - 2) WAITV6();
                else if (kt == NT - 2) WAITV3(); else WAITV0(); });
    }
    #undef STG
    #undef WAITV6
    #undef WAITV3
    #undef WAITV0
    #undef PHASE

#pragma unroll
    for (int i = 0; i < 4; ++i) {
        int Rb = mBase + wm * 64 + i * 16 + lg * 4;
        if (Rb >= 2080) continue;
        float bb[4];
#pragma unroll
        for (int r = 0; r < 4; ++r) bb[r] = bias[Rb + r];
#pragma unroll
        for (int j = 0; j < 4; ++j) {
            int Cg = nBase + wn * 64 + j * 16 + lq;
            int b = Cg >> 11, t = Cg & (T_ - 1);
#pragma unroll
            for (int r = 0; r < 4; ++r) {
                int R = Rb + r;
                float v = acc[i][j][r] + bb[r];
                if (Rb < 1024) {
                    xbaseT[((size_t)b * C_ + R) * T_ + t] = v;
                } else if (Rb < 2048) {
                    deltaT[((size_t)b * C_ + (R - 1024)) * T_ + t] =
                        softplus_f(v);
                } else if (Rb < 2064) {
                    BmT[((size_t)b * S_ + (R - 2048)) * T_ + t] = v;
                } else {
                    CmT[((size_t)b * S_ + (R - 2064)) * T_ + t] = v;
                }
            }
        }
    }
}

// ---------------------------------------------------------------------------
// 256x256 bf16 MFMA GEMM, 8-phase counted-vmcnt schedule (R7-verified:
// QKV ~62 us). mode 2: fused QKV (Q/K heads, V transposed).
// ---------------------------------------------------------------------------
__global__ __launch_bounds__(512, 2) void gemm_mfma256(
    const unsigned short* __restrict__ A, const unsigned short* __restrict__ Bm,
    const float* __restrict__ bias,
    void* __restrict__ outv, void* __restrict__ out2,
    void* __restrict__ out3,
    int M, int N, int K, int lda)
{
    __shared__ __align__(16) unsigned short AS[2][2][8192];
    __shared__ __align__(16) unsigned short BS[2][2][8192];

    const int tid = threadIdx.x;              // 0..511
    const int w = tid >> 6, lane = tid & 63;
    const int lq = lane & 15, lg = lane >> 4;
    const int wm = w >> 2, wn = w & 3;        // 2 x 4 wave grid
    const int mBase = blockIdx.y * 256, nBase = blockIdx.x * 256;

    const int c0 = tid, c1 = tid + 512;
    const int r0 = ((c0 >> 6) << 4) | (c0 & 15), k0l = ((c0 >> 4) & 3) << 3;
    const int r1 = ((c1 >> 6) << 4) | (c1 & 15), k1l = ((c1 >> 4) & 3) << 3;
    const unsigned short* gA0 = A  + (size_t)(mBase + r0) * lda + k0l;
    const unsigned short* gA1 = A  + (size_t)(mBase + r1) * lda + k1l;
    const unsigned short* gB0 = Bm + (size_t)(nBase + r0) * lda + k0l;
    const unsigned short* gB1 = Bm + (size_t)(nBase + r1) * lda + k1l;

    f32x4 acc[8][4];
#pragma unroll
    for (int i = 0; i < 8; ++i)
#pragma unroll
        for (int j = 0; j < 4; ++j) acc[i][j] = (f32x4){0.f, 0.f, 0.f, 0.f};

    #define STG_A(buf_, half_, kb_)                                           \
        do {                                                                  \
            gload16(gA0 + (kb_) + (half_) * 32, &AS[buf_][half_][c0 * 8]);    \
            gload16(gA1 + (kb_) + (half_) * 32, &AS[buf_][half_][c1 * 8]);    \
        } while (0)
    #define STG_B(buf_, half_, kb_)                                           \
        do {                                                                  \
            gload16(gB0 + (kb_) + (half_) * 32, &BS[buf_][half_][c0 * 8]);    \
            gload16(gB1 + (kb_) + (half_) * 32, &BS[buf_][half_][c1 * 8]);    \
        } while (0)
    #define WAITV8() asm volatile("s_waitcnt vmcnt(8)" ::: "memory")
    #define WAITV4() asm volatile("s_waitcnt vmcnt(4)" ::: "memory")
    #define WAITV0() asm volatile("s_waitcnt vmcnt(0)" ::: "memory")

    #define PHASE(buf_, half_, qi_, STAGE_STMT, GATE_STMT)                    \
        do {                                                                  \
            short8 a_[4];                                                     \
            _Pragma("unroll")                                                 \
            for (int i = 0; i < 4; ++i)                                       \
                a_[i] = *(const short8*)&AS[buf_][half_]                      \
                    [((wm * 8 + (qi_) * 4 + i) * 64 + lg * 16 + lq) * 8];     \
            if ((qi_) == 0) {                                                 \
                _Pragma("unroll")                                             \
                for (int j = 0; j < 4; ++j)                                   \
                    bfr[j] = *(const short8*)&BS[buf_][half_]                 \
                        [((wn * 4 + j) * 64 + lg * 16 + lq) * 8];             \
            }                                                                 \
            STAGE_STMT;                                                       \
            __builtin_amdgcn_s_barrier();                                     \
            asm volatile("s_waitcnt lgkmcnt(0)" ::: "memory");                \
            __builtin_amdgcn_s_setprio(1);                                    \
            _Pragma("unroll")                                                 \
            for (int i = 0; i < 4; ++i)                                       \
                _Pragma("unroll")                                             \
                for (int j = 0; j < 4; ++j)                                   \
                    acc[(qi_) * 4 + i][j] =                                   \
                        __builtin_amdgcn_mfma_f32_16x16x32_bf16(              \
                            a_[i], bfr[j], acc[(qi_) * 4 + i][j], 0, 0, 0);   \
            __builtin_amdgcn_s_setprio(0);                                    \
            GATE_STMT;                                                        \
            __builtin_amdgcn_s_barrier();                                     \
        } while (0)

    STG_A(0, 0, 0);
    STG_B(0, 0, 0);
    STG_A(0, 1, 0);
    STG_B(0, 1, 0);
    STG_A(1, 0, 64);
    STG_B(1, 0, 64);
    WAITV8();
    __builtin_amdgcn_s_barrier();

    const int NT = K >> 6;
    for (int kt = 0; kt < NT; ++kt) {
        const int buf = kt & 1, nbuf = buf ^ 1;
        const int kb1 = (kt + 1) << 6, kb2 = (kt + 2) << 6;
        short8 bfr[4];
        PHASE(buf, 0, 0, { if (kt + 1 < NT) STG_A(nbuf, 1, kb1); }, {});
        PHASE(buf, 0, 1, { if (kt + 1 < NT) STG_B(nbuf, 1, kb1); },
              { if (kt < NT - 1) WAITV8(); else WAITV0(); });
        PHASE(buf, 1, 0, { if (kt + 2 < NT) STG_A(buf, 0, kb2); }, {});
        PHASE(buf, 1, 1, { if (kt + 2 < NT) STG_B(buf, 0, kb2); },
              { if (kt < NT - 2) WAITV8();
                else if (kt == NT - 2) WAITV4(); });
    }
    #undef STG_A
    #undef STG_B
    #undef WAITV8
    #undef WAITV4
    #undef WAITV0
    #undef PHASE

    // mode 2: QKV epilogue
    unsigned short* Qb  = (unsigned short*)outv;
    unsigned short* Kb  = (unsigned short*)out2;
    unsigned short* VTb = (unsigned short*)out3;
#pragma unroll
    for (int j = 0; j < 4; ++j) {
        int Cg = nBase + wn * 64 + j * 16 + lq;
        int reg = Cg >> 10, c = Cg & 1023;
        int h = c >> 6, hd = c & 63;
        float bb = bias[Cg];
#pragma unroll
        for (int i = 0; i < 8; ++i) {
            int Rb = mBase + wm * 128 + i * 16 + lg * 4;
#pragma unroll
            for (int r = 0; r < 4; ++r) {
                int R = Rb + r, b = R >> 11, t = R & (T_ - 1);
                unsigned short o = f2bf(acc[i][j][r] + bb);
                if (reg == 0)
                    Qb[(((size_t)(b * H_ + h) * T_ + t) * HD_) + hd] = o;
                else if (reg == 1)
                    Kb[(((size_t)(b * H_ + h) * T_ + t) * HD_) + hd] = o;
                else
                    VTb[(((size_t)(b * H_ + h) * HD_ + hd) * T_) + t] = o;
            }
        }
    }
}

// ---------------------------------------------------------------------------
// Chunked scan, FOLD=4, NCH=64 (2048 blocks -> full wave-slot subscription)
// + 1-deep register prefetch in all load loops (latency hiding: scan was
// latency-bound at 37% occupancy, 550 GB/s, VALU 22%).
// Pbuf lives over dead xb [0,8MB); Lbuf uses d_out as scratch (dead until
// the final Wo GEMM overwrites every element).
// ---------------------------------------------------------------------------
__global__ __launch_bounds__(256) void scan_partial(
    const float* __restrict__ xbaseT, const float* __restrict__ deltaT,
    const float* __restrict__ BmT, const float* __restrict__ A_log,
    float4* __restrict__ Pbuf, float4* __restrict__ Lbuf)
{
    const int tid = threadIdx.x;
    const int s4 = tid & 3;
    const int cm = tid >> 2;
    const int cg = blockIdx.x & 15;
    const int k  = (blockIdx.x >> 4) & (NCH - 1);
    const int b  = blockIdx.x >> 10;
    const int c  = cg * 64 + cm;

    float a[4];
#pragma unroll
    for (int j = 0; j < 4; ++j)
        a[j] = -__expf(A_log[c * S_ + s4 * 4 + j]);

    const int tb = k * CHL;
    const float* dp = deltaT + ((size_t)b * C_ + c) * T_ + tb;
    const float* xp = xbaseT + ((size_t)b * C_ + c) * T_ + tb;
    const float* bp = BmT + ((size_t)(b * S_ + s4 * 4)) * T_ + tb;

    float L[4] = {0.f, 0.f, 0.f, 0.f};
    float sumd = 0.f;

    // prefetch t0 = 0
    float4 d4 = *(const float4*)&dp[0];
    float4 x4 = *(const float4*)&xp[0];
    float4 b4[4];
#pragma unroll
    for (int j = 0; j < 4; ++j) b4[j] = *(const float4*)&bp[(size_t)j * T_];

    for (int t0 = 0; t0 < CHL; t0 += 4) {
        const int tn = (t0 + 4 < CHL) ? t0 + 4 : t0;   // uniform, always valid
        float4 d4n = *(const float4*)&dp[tn];
        float4 x4n = *(const float4*)&xp[tn];
        float4 b4n[4];
#pragma unroll
        for (int j = 0; j < 4; ++j)
            b4n[j] = *(const float4*)&bp[(size_t)j * T_ + tn];

        float dv[4] = {d4.x, d4.y, d4.z, d4.w};
        float xv[4] = {x4.x, x4.y, x4.z, x4.w};
        float bv[4][4];
#pragma unroll
        for (int j = 0; j < 4; ++j) {
            bv[j][0] = b4[j].x; bv[j][1] = b4[j].y;
            bv[j][2] = b4[j].z; bv[j][3] = b4[j].w;
        }
#pragma unroll
        for (int q = 0; q < 4; ++q) {
            float u = dv[q] * xv[q];
            sumd += dv[q];
#pragma unroll
            for (int j = 0; j < 4; ++j)
                L[j] = fmaf(__expf(dv[q] * a[j]), L[j], u * bv[j][q]);
        }
        d4 = d4n; x4 = x4n;
#pragma unroll
        for (int j = 0; j < 4; ++j) b4[j] = b4n[j];
    }
    int gid = blockIdx.x * 256 + tid;
    float4 P4 = {__expf(a[0] * sumd), __expf(a[1] * sumd),
                 __expf(a[2] * sumd), __expf(a[3] * sumd)};
    float4 L4 = {L[0], L[1], L[2], L[3]};
    Pbuf[gid] = P4;
    Lbuf[gid] = L4;
}

__global__ __launch_bounds__(256) void scan_final(
    const float* __restrict__ xbaseT, const float* __restrict__ deltaT,
    const float* __restrict__ BmT, const float* __restrict__ CmT,
    const float* __restrict__ A_log, const float4* __restrict__ Pbuf,
    const float4* __restrict__ Lbuf, float* __restrict__ hyb)
{
    const int tid = threadIdx.x;
    const int s4 = tid & 3;
    const int cm = tid >> 2;
    const int cg = blockIdx.x & 15;
    const int k  = (blockIdx.x >> 4) & (NCH - 1);
    const int b  = blockIdx.x >> 10;
    const int c  = cg * 64 + cm;

    float h[4] = {0.f, 0.f, 0.f, 0.f};
    if (k > 0) {
        // prefix combine with 1-deep prefetch (loads independent of h-chain)
        const size_t g0 = (size_t)(((b * NCH) << 4) + cg) * 256 + tid;
        float4 P4 = Pbuf[g0], L4 = Lbuf[g0];
        for (int k2 = 1; k2 < k; ++k2) {
            size_t gn = g0 + (size_t)k2 * 4096;
            float4 P4n = Pbuf[gn], L4n = Lbuf[gn];
            h[0] = fmaf(P4.x, h[0], L4.x);
            h[1] = fmaf(P4.y, h[1], L4.y);
            h[2] = fmaf(P4.z, h[2], L4.z);
            h[3] = fmaf(P4.w, h[3], L4.w);
            P4 = P4n; L4 = L4n;
        }
        h[0] = fmaf(P4.x, h[0], L4.x);
        h[1] = fmaf(P4.y, h[1], L4.y);
        h[2] = fmaf(P4.z, h[2], L4.z);
        h[3] = fmaf(P4.w, h[3], L4.w);
    }

    float a[4];
#pragma unroll
    for (int j = 0; j < 4; ++j)
        a[j] = -__expf(A_log[c * S_ + s4 * 4 + j]);

    const int tb = k * CHL;
    const float* dp = deltaT + ((size_t)b * C_ + c) * T_ + tb;
    const float* xp = xbaseT + ((size_t)b * C_ + c) * T_ + tb;
    const float* bp = BmT + ((size_t)(b * S_ + s4 * 4)) * T_ + tb;
    const float* cp = CmT + ((size_t)(b * S_ + s4 * 4)) * T_ + tb;
    float* hp = hyb + ((size_t)b * T_ + tb) * C_ + c;

    // prefetch t0 = 0
    float4 d4 = *(const float4*)&dp[0];
    float4 x4 = *(const float4*)&xp[0];
    float4 b4[4], c4[4];
#pragma unroll
    for (int j = 0; j < 4; ++j) {
        b4[j] = *(const float4*)&bp[(size_t)j * T_];
        c4[j] = *(const float4*)&cp[(size_t)j * T_];
    }

    for (int t0 = 0; t0 < CHL; t0 += 4) {
        const int tn = (t0 + 4 < CHL) ? t0 + 4 : t0;
        float4 d4n = *(const float4*)&dp[tn];
        float4 x4n = *(const float4*)&xp[tn];
        float4 b4n[4], c4n[4];
#pragma unroll
        for (int j = 0; j < 4; ++j) {
            b4n[j] = *(const float4*)&bp[(size_t)j * T_ + tn];
            c4n[j] = *(const float4*)&cp[(size_t)j * T_ + tn];
        }

        float dv[4] = {d4.x, d4.y, d4.z, d4.w};
        float xv[4] = {x4.x, x4.y, x4.z, x4.w};
        float bv[4][4], cv[4][4];
#pragma unroll
        for (int j = 0; j < 4; ++j) {
            bv[j][0] = b4[j].x; bv[j][1] = b4[j].y;
            bv[j][2] = b4[j].z; bv[j][3] = b4[j].w;
            cv[j][0] = c4[j].x; cv[j][1] = c4[j].y;
            cv[j][2] = c4[j].z; cv[j][3] = c4[j].w;
        }
#pragma unroll
        for (int q = 0; q < 4; ++q) {
            float u = dv[q] * xv[q];
#pragma unroll
            for (int j = 0; j < 4; ++j)
                h[j] = fmaf(__expf(dv[q] * a[j]), h[j], u * bv[j][q]);
            float y = h[0] * cv[0][q];
            y = fmaf(h[1], cv[1][q], y);
            y = fmaf(h[2], cv[2][q], y);
            y = fmaf(h[3], cv[3][q], y);
            y += __shfl_xor(y, 1, 64);
            y += __shfl_xor(y, 2, 64);
            if (s4 == 0) hp[(size_t)(t0 + q) * C_] = xv[q] + y;
        }
        d4 = d4n; x4 = x4n;
#pragma unroll
        for (int j = 0; j < 4; ++j) { b4[j] = b4n[j]; c4[j] = c4n[j]; }
    }
}

// ---------------------------------------------------------------------------
// LayerNorm over C=1024, bf16 output.
// ---------------------------------------------------------------------------
__global__ __launch_bounds__(256) void layernorm_kernel(
    const float* __restrict__ in, const float* __restrict__ g,
    const float* __restrict__ beta, unsigned short* __restrict__ out)
{
    const int row = blockIdx.x;
    const float* rp = in + (size_t)row * C_;
    const int c = threadIdx.x * 4;
    float4 v = *(const float4*)&rp[c];
    float sum = v.x + v.y + v.z + v.w;
    float sq = v.x * v.x + v.y * v.y + v.z * v.z + v.w * v.w;
#pragma unroll
    for (int off = 1; off < 64; off <<= 1) {
        sum += __shfl_xor(sum, off, 64);
        sq += __shfl_xor(sq, off, 64);
    }
    __shared__ float sS[4], sQ[4];
    int wave = threadIdx.x >> 6, lane = threadIdx.x & 63;
    if (lane == 0) { sS[wave] = sum; sQ[wave] = sq; }
    __syncthreads();
    sum = sS[0] + sS[1] + sS[2] + sS[3];
    sq = sQ[0] + sQ[1] + sQ[2] + sQ[3];
    const float mu = sum * (1.f / C_);
    const float var = sq * (1.f / C_) - mu * mu;
    const float rstd = rsqrtf(var + 1e-5f);
    float4 gg = *(const float4*)&g[c];
    float4 bb = *(const float4*)&beta[c];
    ushort4v o;
    o.x = f2bf((v.x - mu) * rstd * gg.x + bb.x);
    o.y = f2bf((v.y - mu) * rstd * gg.y + bb.y);
    o.z = f2bf((v.z - mu) * rstd * gg.z + bb.z);
    o.w = f2bf((v.w - mu) * rstd * gg.w + bb.w);
    *(ushort4v*)&out[(size_t)row * C_ + c] = o;
}

// ---------------------------------------------------------------------------
// MFMA flash attention v2: BK=128, register-prefetch pipeline, ones-column
// row-sum trick, Q fragments in registers. q-tile pair (31-p, p).
// ---------------------------------------------------------------------------
#define BKT 128
#define KP  72
#define VP  136
__global__ __launch_bounds__(256) void attn_mfma(
    const unsigned short* __restrict__ Q, const unsigned short* __restrict__ K,
    const unsigned short* __restrict__ VT, const float* __restrict__ temp,
    unsigned short* __restrict__ out)
{
    __shared__ __align__(16) unsigned short Ks[BKT * KP];
    __shared__ __align__(16) unsigned short Vs[80 * VP];
    __shared__ __align__(16) unsigned short Ps[64 * VP];

    const int tid = threadIdx.x;
    const int w = tid >> 6, lane = tid & 63;
    const int lq = lane & 15, lg = lane >> 4;
    const int p  = blockIdx.x & 15;
    const int bh = blockIdx.x >> 4;
    const int b = bh >> 4, h = bh & 15;

    const float scale = softplus_f(temp[h]) * 0.125f;
    const unsigned short* Qp = Q + (size_t)bh * T_ * HD_;
    const unsigned short* Kp = K + (size_t)bh * T_ * HD_;
    const unsigned short* Vp = VT + (size_t)bh * HD_ * T_;

    {
        int r = 64 + (tid >> 4), o = (tid & 15) * 8;
        ushort8 ones = {0x3f80, 0x3f80, 0x3f80, 0x3f80,
                        0x3f80, 0x3f80, 0x3f80, 0x3f80};
        *(ushort8*)&Vs[r * VP + o] = ones;
    }

    ushort8 kreg[4], vreg[4];
    #define LOADKV(jtv)                                                        \
        do {                                                                   \
            int kb = (jtv) * BKT;                                              \
            _Pragma("unroll")                                                  \
            for (int q2 = 0; q2 < 4; ++q2) {                                   \
                int c = tid + q2 * 256;                                        \
                kreg[q2] = *(const ushort8*)&Kp[(size_t)(kb + (c >> 3)) * HD_  \
                                                + (c & 7) * 8];                \
                vreg[q2] = *(const ushort8*)&Vp[(size_t)(c >> 4) * T_ + kb     \
                                                + (c & 15) * 8];               \
            }                                                                  \
        } while (0)

    for (int half = 0; half < 2; ++half) {
        const int qi = half ? p : (31 - p);
        const int qbase = qi * 64;
        const int nT = (qbase + 64 + BKT - 1) / BKT;

        short8 qf[2];
#pragma unroll
        for (int s = 0; s < 2; ++s)
            qf[s] = *(const short8*)&Qp[(size_t)(qbase + w * 16 + lq) * HD_
                                        + s * 32 + lg * 8];
        LOADKV(0);

        float m_i[4];
        f32x4 o[5];
#pragma unroll
        for (int r = 0; r < 4; ++r) m_i[r] = -INFINITY;
#pragma unroll
        for (int j = 0; j < 5; ++j) o[j] = (f32x4){0.f, 0.f, 0.f, 0.f};

        for (int jt = 0; jt < nT; ++jt) {
            const int kbase = jt * BKT;
            const bool last = (jt == nT - 1);
            __syncthreads();
#pragma unroll
            for (int q2 = 0; q2 < 4; ++q2) {
                int c = tid + q2 * 256;
                *(ushort8*)&Ks[(c >> 3) * KP + (c & 7) * 8] = kreg[q2];
                *(ushort8*)&Vs[(c >> 4) * VP + (c & 15) * 8] = vreg[q2];
            }
            __syncthreads();
            if (jt + 1 < nT) LOADKV(jt + 1);

            f32x4 sacc[8];
#pragma unroll
            for (int j = 0; j < 8; ++j) sacc[j] = (f32x4){0.f, 0.f, 0.f, 0.f};
#pragma unroll
            for (int s = 0; s < 2; ++s) {
#pragma unroll
                for (int j = 0; j < 8; ++j) {
                    short8 kf = *(const short8*)&Ks[(j * 16 + lq) * KP
                                                    + s * 32 + lg * 8];
                    sacc[j] = __builtin_amdgcn_mfma_f32_16x16x32_bf16(
                        qf[s], kf, sacc[j], 0, 0, 0);
                }
            }

#pragma unroll
            for (int r = 0; r < 4; ++r) {
                int qrow = qbase + w * 16 + lg * 4 + r;
                float sv[8];
#pragma unroll
                for (int j = 0; j < 8; ++j) {
                    sv[j] = sacc[j][r] * scale;
                    if (last && (kbase + j * 16 + lq > qrow)) sv[j] = -INFINITY;
                }
                float mx = sv[0];
#pragma unroll
                for (int j = 1; j < 8; ++j) mx = fmaxf(mx, sv[j]);
                mx = fmaxf(mx, __shfl_xor(mx, 1, 64));
                mx = fmaxf(mx, __shfl_xor(mx, 2, 64));
                mx = fmaxf(mx, __shfl_xor(mx, 4, 64));
                mx = fmaxf(mx, __shfl_xor(mx, 8, 64));
                float mnew = fmaxf(m_i[r], mx);
                float alpha = __expf(m_i[r] - mnew);
                m_i[r] = mnew;
#pragma unroll
                for (int j = 0; j < 5; ++j) o[j][r] *= alpha;
#pragma unroll
                for (int j = 0; j < 8; ++j)
                    Ps[(w * 16 + lg * 4 + r) * VP + j * 16 + lq] =
                        f2bf(__expf(sv[j] - mnew));
            }

#pragma unroll
            for (int s2 = 0; s2 < 4; ++s2) {
                short8 pf = *(const short8*)&Ps[(w * 16 + lq) * VP
                                                + s2 * 32 + lg * 8];
#pragma unroll
                for (int j = 0; j < 5; ++j) {
                    short8 vf = *(const short8*)&Vs[(j * 16 + lq) * VP
                                                    + s2 * 32 + lg * 8];
                    o[j] = __builtin_amdgcn_mfma_f32_16x16x32_bf16(
                        pf, vf, o[j], 0, 0, 0);
                }
            }
        }

#pragma unroll
        for (int r = 0; r < 4; ++r) {
            float inv = 1.f / o[4][r];
            int qrow = qbase + w * 16 + lg * 4 + r;
#pragma unroll
            for (int j = 0; j < 4; ++j)
                out[((size_t)(b * T_ + qrow)) * C_ + h * 64 + j * 16 + lq] =
                    f2bf(o[j][r] * inv);
        }
    }
    #undef LOADKV
}

// ---------------------------------------------------------------------------
extern "C" void kernel_launch(void* const* d_in, const int* in_sizes, int n_in,
                              void* d_out, int out_size, void* d_ws, size_t ws_size,
                              hipStream_t stream)
{
    const float* x     = (const float*)d_in[0];
    const float* A_log = (const float*)d_in[1];
    const float* Wd    = (const float*)d_in[2];
    const float* bd    = (const float*)d_in[3];
    const float* WB    = (const float*)d_in[4];
    const float* WC    = (const float*)d_in[5];
    const float* Wq    = (const float*)d_in[6];
    const float* bq    = (const float*)d_in[7];
    const float* Wk    = (const float*)d_in[8];
    const float* bk    = (const float*)d_in[9];
    const float* Wv    = (const float*)d_in[10];
    const float* bv    = (const float*)d_in[11];
    const float* Wx    = (const float*)d_in[12];
    const float* bx    = (const float*)d_in[13];
    const float* Wo    = (const float*)d_in[14];
    const float* bo    = (const float*)d_in[15];
    const float* ln_g  = (const float*)d_in[16];
    const float* ln_b  = (const float*)d_in[17];
    const float* temp  = (const float*)d_in[18];

    char* wsb = (char*)d_ws;
    const size_t MB = 1024 * 1024;
    const size_t HMB = 512 * 1024;
    // Workspace (timeline-disjoint; NCH=64):
    //  [0,8):      xb (dead after projT) -> Pbuf (8 MB) -> hybrid (layernorm)
    //  [8,12.5):   Astack + biasPD/biasQKV
    //  [12.5,18.5): WqkvT
    //  [18.5,34.5): deltaT  ([18.5,20.5) head doubles as WoT post-attention)
    //  [20.5,28.5): Qb (QKV, after scan)
    //  [28.5,36.5): Kb
    //  [34.5,50.5): xbaseT
    //  [36.5,44.5): VTb
    //  [44.5,52.5): attnO
    //  [50.5,66.5): hyb
    //  [66.5,67):  BmT/CmT
    //  Lbuf (8 MB) = d_out scratch: dead until the final Wo GEMM fully
    //  overwrites d_out (scan_partial writes it, scan_final reads it, both
    //  strictly earlier in the stream).
    unsigned short* xb      = (unsigned short*)(wsb);
    float4* Pbuf            = (float4*)(wsb);
    float4* Lbuf            = (float4*)d_out;
    unsigned short* hybrid  = (unsigned short*)(wsb);
    unsigned short* Astack  = (unsigned short*)(wsb + 8 * MB);
    float* biasPD           = (float*)(wsb + 8 * MB + (size_t)2176 * 2048);
    float* biasQKV          = biasPD + 2176;
    unsigned short* WqkvT   = (unsigned short*)(wsb + 12 * MB + HMB);
    unsigned short* WoT     = (unsigned short*)(wsb + 18 * MB + HMB);
    float* deltaT           = (float*)(wsb + 18 * MB + HMB);
    float* xbaseT           = (float*)(wsb + 34 * MB + HMB);
    float* hyb              = (float*)(wsb + 50 * MB + HMB);
    float* BmT              = (float*)(wsb + 66 * MB + HMB);
    float* CmT              = BmT + (size_t)B_ * S_ * T_;
    unsigned short* Qb      = (unsigned short*)(wsb + 20 * MB + HMB);
    unsigned short* Kb      = (unsigned short*)(wsb + 28 * MB + HMB);
    unsigned short* VTb     = (unsigned short*)(wsb + 36 * MB + HMB);
    unsigned short* attnO   = (unsigned short*)(wsb + 44 * MB + HMB);

    // ---- prep ----
    cast_bf16<<<4096, 256, 0, stream>>>(x, xb, (B_ * T_ * C_) / 4);
    wtrans_multi<<<dim3(32, 32, 5), 256, 0, stream>>>(Wx, Wd, Wq, Wk, Wv,
                                                      Astack, WqkvT);
    prep_misc<<<149, 256, 0, stream>>>(WB, WC, bx, bd, bq, bk, bv,
                                       Astack, biasPD, biasQKV);

    // ---- fused projection-T GEMM (hybrid 128x256, 272 blocks) ----
    gemm_projT<<<dim3(16, 17, 1), 512, 0, stream>>>(
        Astack, xb, biasPD, xbaseT, deltaT, BmT, CmT,
        1024, 1024);

    // ---- chunk-parallel scan (FOLD=4, NCH=64 -> 2048 blocks) ----
    const int scanBlocks = B_ * NCH * (C_ / 64);   // 2048
    scan_partial<<<scanBlocks, 256, 0, stream>>>(xbaseT, deltaT, BmT, A_log,
                                                 Pbuf, Lbuf);
    scan_final<<<scanBlocks, 256, 0, stream>>>(xbaseT, deltaT, BmT, CmT, A_log,
                                               Pbuf, Lbuf, hyb);

    // ---- layernorm ----
    layernorm_kernel<<<B_ * T_, 256, 0, stream>>>(hyb, ln_g, ln_b, hybrid);

    // ---- fused QKV GEMM (256^2 8-phase, R7-verified) ----
    gemm_mfma256<<<dim3(12, 16, 1), 512, 0, stream>>>(
        hybrid, WqkvT, biasQKV, Qb, Kb, VTb,
        4096, 3072, 1024, 1024);

    // ---- attention ----
    attn_mfma<<<B_ * H_ * 16, 256, 0, stream>>>(Qb, Kb, VTb, temp, attnO);

    // ---- Wo transpose + single-pass GEMM with fused bias -> d_out ----
    wtrans<<<dim3(32, 32), 256, 0, stream>>>(Wo, WoT);
    gemm_mfma<<<dim3(8, 32, 1), 256, 0, stream>>>(
        attnO, WoT, bo, d_out,
        4096, 1024, 1024, 1024);
}

// Round 11
// 459.170 us; speedup vs baseline: 1.0269x; 1.0269x over previous
//
#include <hip/hip_runtime.h>
#include <math.h>

#define B_  2
#define T_  2048
#define C_  1024
#define H_  16
#define S_  16
#define HD_ 64
#define NCH 32
#define CHL 64   /* T_/NCH */

typedef short  short8  __attribute__((ext_vector_type(8)));
typedef unsigned short ushort8 __attribute__((ext_vector_type(8)));
typedef unsigned short ushort4v __attribute__((ext_vector_type(4)));
typedef float  f32x4   __attribute__((ext_vector_type(4)));

__device__ __forceinline__ float softplus_f(float v) {
    return fmaxf(v, 0.f) + log1pf(__expf(-fabsf(v)));
}

__device__ __forceinline__ unsigned short f2bf(float x) {
    unsigned u = __float_as_uint(x);
    u += 0x7fffu + ((u >> 16) & 1u);
    return (unsigned short)(u >> 16);
}

// async global -> LDS, 16B per lane. LDS dest = wave-uniform base + lane*16.
__device__ __forceinline__ void gload16(const unsigned short* g,
                                        unsigned short* l)
{
    __builtin_amdgcn_global_load_lds(
        (const __attribute__((address_space(1))) unsigned int*)g,
        (__attribute__((address_space(3))) unsigned int*)l, 16, 0, 0);
}

// ---------------------------------------------------------------------------
// cast fp32 -> bf16 (vectorized), n4 = n/4
// ---------------------------------------------------------------------------
__global__ __launch_bounds__(256) void cast_bf16(const float* __restrict__ in,
                                                 unsigned short* __restrict__ out,
                                                 int n4)
{
    int i = blockIdx.x * 256 + threadIdx.x;
    if (i >= n4) return;
    float4 v = ((const float4*)in)[i];
    ushort4v o = {f2bf(v.x), f2bf(v.y), f2bf(v.z), f2bf(v.w)};
    ((ushort4v*)out)[i] = o;
}

// ---------------------------------------------------------------------------
// transpose-cast: W (1024 x 1024 fp32) -> WT (1024 x 1024 bf16, transposed)
// ---------------------------------------------------------------------------
__device__ __forceinline__ void wtrans_body(const float* __restrict__ W,
                                            unsigned short* __restrict__ WT,
                                            int bx, int by, int tid)
{
    __shared__ float t[32][33];
    const int n0 = bx * 32, k0 = by * 32;
    const int tx = tid & 31, ty = tid >> 5;
#pragma unroll
    for (int p = 0; p < 4; ++p)
        t[ty + p * 8][tx] = W[(size_t)(k0 + ty + p * 8) * C_ + n0 + tx];
    __syncthreads();
#pragma unroll
    for (int p = 0; p < 4; ++p)
        WT[(size_t)(n0 + ty + p * 8) * C_ + k0 + tx] = f2bf(t[tx][ty + p * 8]);
}

__global__ __launch_bounds__(256) void wtrans(const float* __restrict__ W,
                                              unsigned short* __restrict__ WT)
{
    wtrans_body(W, WT, blockIdx.x, blockIdx.y, threadIdx.x);
}

// z: 0 Wx->Astack, 1 Wd->Astack+1024 rows, 2 Wq->Wqkv, 3 Wk->+1024, 4 Wv->+2048
__global__ __launch_bounds__(256) void wtrans_multi(
    const float* __restrict__ Wx, const float* __restrict__ Wd,
    const float* __restrict__ Wq, const float* __restrict__ Wk,
    const float* __restrict__ Wv,
    unsigned short* __restrict__ Astack, unsigned short* __restrict__ Wqkv)
{
    const float* src;
    unsigned short* dst;
    switch (blockIdx.z) {
        case 0: src = Wx; dst = Astack; break;
        case 1: src = Wd; dst = Astack + (size_t)1024 * 1024; break;
        case 2: src = Wq; dst = Wqkv; break;
        case 3: src = Wk; dst = Wqkv + (size_t)1024 * 1024; break;
        default: src = Wv; dst = Wqkv + (size_t)2048 * 1024; break;
    }
    wtrans_body(src, dst, blockIdx.x, blockIdx.y, threadIdx.x);
}

// ---------------------------------------------------------------------------
// misc prep: WB/WC transposed into Astack rows 2048..2079 + stacked biases
// ---------------------------------------------------------------------------
__global__ __launch_bounds__(256) void prep_misc(
    const float* __restrict__ WB, const float* __restrict__ WC,
    const float* __restrict__ bx, const float* __restrict__ bd,
    const float* __restrict__ bq, const float* __restrict__ bk,
    const float* __restrict__ bv,
    unsigned short* __restrict__ Astack, float* __restrict__ biasPD,
    float* __restrict__ biasQKV)
{
    int gid = blockIdx.x * 256 + threadIdx.x;
    if (gid < 32768) {
        int w = gid >> 14, rem = gid & 16383;
        int s = rem >> 10, k = rem & 1023;
        const float* src = w ? WC : WB;
        Astack[(size_t)(2048 + w * 16 + s) * 1024 + k] = f2bf(src[k * 16 + s]);
    } else {
        int id = gid - 32768;
        if (id < 2176) {
            biasPD[id] = id < 1024 ? bx[id] : (id < 2048 ? bd[id - 1024] : 0.f);
        } else {
            int id2 = id - 2176;
            if (id2 < 3072)
                biasQKV[id2] = id2 < 1024 ? bq[id2]
                             : (id2 < 2048 ? bk[id2 - 1024] : bv[id2 - 2048]);
        }
    }
}

// ---------------------------------------------------------------------------
// bf16 MFMA GEMM: acc = A(M x K) @ B(N x K)^T, both lda-strided K-major bf16.
// 128x128 tile, BK=32, 256 threads = 4 waves (2x2 of 64x64).
// R2-verified 4-buffer counted-vmcnt pipeline.
// K must be a multiple of 128 (1024 here).
// mode 0: direct fp32 out with bias (Wo projection -> d_out)
// ---------------------------------------------------------------------------
__global__ __launch_bounds__(256) void gemm_mfma(
    const unsigned short* __restrict__ A, const unsigned short* __restrict__ Bm,
    const float* __restrict__ bias,
    void* __restrict__ outv,
    int M, int N, int K, int lda)
{
    __shared__ __align__(16) unsigned short As[4][4096];
    __shared__ __align__(16) unsigned short Bs[4][4096];

    const int tid = threadIdx.x;
    const int w = tid >> 6, lane = tid & 63;
    const int lq = lane & 15, lg = lane >> 4;
    const int wm = w >> 1, wn = w & 1;
    const int mBase = blockIdx.y * 128, nBase = blockIdx.x * 128;

    const int c0 = tid, c1 = tid + 256;
    const int rA0 = ((c0 >> 6) << 4) + (c0 & 15), kO0 = ((c0 >> 4) & 3) << 3;
    const int rA1 = ((c1 >> 6) << 4) + (c1 & 15), kO1 = ((c1 >> 4) & 3) << 3;

    const int wL0 = w * 512;
    const int wL1 = 2048 + w * 512;

    f32x4 acc[4][4];
#pragma unroll
    for (int i = 0; i < 4; ++i)
#pragma unroll
        for (int j = 0; j < 4; ++j) acc[i][j] = (f32x4){0.f, 0.f, 0.f, 0.f};

    const unsigned short* ga0 = A  + (size_t)(mBase + rA0) * lda + kO0;
    const unsigned short* ga1 = A  + (size_t)(mBase + rA1) * lda + kO1;
    const unsigned short* gb0 = Bm + (size_t)(nBase + rA0) * lda + kO0;
    const unsigned short* gb1 = Bm + (size_t)(nBase + rA1) * lda + kO1;

    #define STAGE(bufv, k0v)                               \
        do {                                               \
            gload16(ga0 + (k0v), &As[bufv][wL0]);          \
            gload16(ga1 + (k0v), &As[bufv][wL1]);          \
            gload16(gb0 + (k0v), &Bs[bufv][wL0]);          \
            gload16(gb1 + (k0v), &Bs[bufv][wL1]);          \
        } while (0)
    #define COMPUTE(bufv)                                                       \
        do {                                                                    \
            short8 a[4], b[4];                                                  \
            _Pragma("unroll")                                                   \
            for (int i = 0; i < 4; ++i)                                         \
                a[i] = *(const short8*)&As[bufv][((wm * 4 + i) * 64 + lg * 16 + lq) * 8]; \
            _Pragma("unroll")                                                   \
            for (int j = 0; j < 4; ++j)                                         \
                b[j] = *(const short8*)&Bs[bufv][((wn * 4 + j) * 64 + lg * 16 + lq) * 8]; \
            _Pragma("unroll")                                                   \
            for (int i = 0; i < 4; ++i)                                         \
                _Pragma("unroll")                                               \
                for (int j = 0; j < 4; ++j)                                     \
                    acc[i][j] = __builtin_amdgcn_mfma_f32_16x16x32_bf16(        \
                        a[i], b[j], acc[i][j], 0, 0, 0);                        \
        } while (0)
    #define WAITV4() asm volatile("s_waitcnt vmcnt(4)" ::: "memory")
    #define WAITV0() asm volatile("s_waitcnt vmcnt(0)" ::: "memory")
    #define LGKM0()  asm volatile("s_waitcnt lgkmcnt(0)" ::: "memory")
    #define STEP(cbuf, kt)                                          \
        do {                                                        \
            if ((kt) + 32 < K) WAITV4(); else WAITV0();             \
            LGKM0();                                                \
            __builtin_amdgcn_s_barrier();                           \
            if ((kt) + 64 < K) STAGE(((cbuf) + 2) & 3, (kt) + 64);  \
            COMPUTE(cbuf);                                          \
        } while (0)

    STAGE(0, 0);
    STAGE(1, 32);

    for (int k0 = 0; k0 < K; k0 += 128) {
        STEP(0, k0);
        STEP(1, k0 + 32);
        STEP(2, k0 + 64);
        STEP(3, k0 + 96);
    }
    #undef STAGE
    #undef COMPUTE
    #undef WAITV4
    #undef WAITV0
    #undef LGKM0
    #undef STEP

    // direct fp32 output with bias over N columns (Wo projection)
    float* O = (float*)outv;
#pragma unroll
    for (int j = 0; j < 4; ++j) {
        int Cg = nBase + wn * 64 + j * 16 + lq;
        float bb = bias[Cg];
#pragma unroll
        for (int i = 0; i < 4; ++i) {
            int Rb = mBase + wm * 64 + i * 16 + lg * 4;
#pragma unroll
            for (int r = 0; r < 4; ++r)
                O[(size_t)(Rb + r) * N + Cg] = acc[i][j][r] + bb;
        }
    }
}

// ---------------------------------------------------------------------------
// projT hybrid GEMM: BM=128, BN=256, BK=64, 512 thr = 8 waves (2M x 4N).
// Counted-vmcnt 2-phase-per-K-tile schedule, 272 blocks. (R8-verified.)
// ---------------------------------------------------------------------------
__global__ __launch_bounds__(512, 2) void gemm_projT(
    const unsigned short* __restrict__ A, const unsigned short* __restrict__ Bm,
    const float* __restrict__ bias,
    float* __restrict__ xbaseT, float* __restrict__ deltaT,
    float* __restrict__ BmT, float* __restrict__ CmT,
    int K, int lda)
{
    __shared__ __align__(16) unsigned short AS[2][2][4096];   // 128 x 32
    __shared__ __align__(16) unsigned short BS[2][2][8192];   // 256 x 32

    const int tid = threadIdx.x;              // 0..511
    const int w = tid >> 6, lane = tid & 63;
    const int lq = lane & 15, lg = lane >> 4;
    const int wm = w >> 2, wn = w & 3;        // 2M x 4N wave grid
    const int mBase = blockIdx.y * 128, nBase = blockIdx.x * 256;

    const int rA = ((tid >> 6) << 4) | (tid & 15);
    const int kA = ((tid >> 4) & 3) << 3;
    const unsigned short* gA = A + (size_t)(mBase + rA) * lda + kA;
    const int eA = tid * 8;
    const int c0 = tid, c1 = tid + 512;
    const int rB0 = ((c0 >> 6) << 4) | (c0 & 15), kB0 = ((c0 >> 4) & 3) << 3;
    const int rB1 = ((c1 >> 6) << 4) | (c1 & 15), kB1 = ((c1 >> 4) & 3) << 3;
    const unsigned short* gB0 = Bm + (size_t)(nBase + rB0) * lda + kB0;
    const unsigned short* gB1 = Bm + (size_t)(nBase + rB1) * lda + kB1;

    f32x4 acc[4][4];
#pragma unroll
    for (int i = 0; i < 4; ++i)
#pragma unroll
        for (int j = 0; j < 4; ++j) acc[i][j] = (f32x4){0.f, 0.f, 0.f, 0.f};

    #define STG(buf_, half_, kb_)                                             \
        do {                                                                  \
            gload16(gA  + (kb_) + (half_) * 32, &AS[buf_][half_][eA]);        \
            gload16(gB0 + (kb_) + (half_) * 32, &BS[buf_][half_][c0 * 8]);    \
            gload16(gB1 + (kb_) + (half_) * 32, &BS[buf_][half_][c1 * 8]);    \
        } while (0)
    #define WAITV6() asm volatile("s_waitcnt vmcnt(6)" ::: "memory")
    #define WAITV3() asm volatile("s_waitcnt vmcnt(3)" ::: "memory")
    #define WAITV0() asm volatile("s_waitcnt vmcnt(0)" ::: "memory")

    #define PHASE(buf_, half_, STAGE_STMT, GATE_STMT)                         \
        do {                                                                  \
            short8 a_[4], b_[4];                                              \
            _Pragma("unroll")                                                 \
            for (int i = 0; i < 4; ++i)                                       \
                a_[i] = *(const short8*)&AS[buf_][half_]                      \
                    [((wm * 4 + i) * 64 + lg * 16 + lq) * 8];                 \
            _Pragma("unroll")                                                 \
            for (int j = 0; j < 4; ++j)                                       \
                b_[j] = *(const short8*)&BS[buf_][half_]                      \
                    [((wn * 4 + j) * 64 + lg * 16 + lq) * 8];                 \
            STAGE_STMT;                                                       \
            __builtin_amdgcn_s_barrier();                                     \
            asm volatile("s_waitcnt lgkmcnt(0)" ::: "memory");                \
            __builtin_amdgcn_s_setprio(1);                                    \
            _Pragma("unroll")                                                 \
            for (int i = 0; i < 4; ++i)                                       \
                _Pragma("unroll")                                             \
                for (int j = 0; j < 4; ++j)                                   \
                    acc[i][j] = __builtin_amdgcn_mfma_f32_16x16x32_bf16(      \
                        a_[i], b_[j], acc[i][j], 0, 0, 0);                    \
            __builtin_amdgcn_s_setprio(0);                                    \
            GATE_STMT;                                                        \
            __builtin_amdgcn_s_barrier();                                     \
        } while (0)

    STG(0, 0, 0);
    STG(0, 1, 0);
    STG(1, 0, 64);
    WAITV6();
    __builtin_amdgcn_s_barrier();

    const int NT = K >> 6;                    // 16
    for (int kt = 0; kt < NT; ++kt) {
        const int buf = kt & 1, nbuf = buf ^ 1;
        const int kb1 = (kt + 1) << 6, kb2 = (kt + 2) << 6;
        PHASE(buf, 0, { if (kt + 1 < NT) STG(nbuf, 1, kb1); },
              { if (kt < NT - 1) WAITV6(); else WAITV3(); });
        PHASE(buf, 1, { if (kt + 2 < NT) STG(buf, 0, kb2); },
              { if (kt < NT - 2) WAITV6();
                else if (kt == NT - 2) WAITV3(); else WAITV0(); });
    }
    #undef STG
    #undef WAITV6
    #undef WAITV3
    #undef WAITV0
    #undef PHASE

#pragma unroll
    for (int i = 0; i < 4; ++i) {
        int Rb = mBase + wm * 64 + i * 16 + lg * 4;
        if (Rb >= 2080) continue;
        float bb[4];
#pragma unroll
        for (int r = 0; r < 4; ++r) bb[r] = bias[Rb + r];
#pragma unroll
        for (int j = 0; j < 4; ++j) {
            int Cg = nBase + wn * 64 + j * 16 + lq;
            int b = Cg >> 11, t = Cg & (T_ - 1);
#pragma unroll
            for (int r = 0; r < 4; ++r) {
                int R = Rb + r;
                float v = acc[i][j][r] + bb[r];
                if (Rb < 1024) {
                    xbaseT[((size_t)b * C_ + R) * T_ + t] = v;
                } else if (Rb < 2048) {
                    deltaT[((size_t)b * C_ + (R - 1024)) * T_ + t] =
                        softplus_f(v);
                } else if (Rb < 2064) {
                    BmT[((size_t)b * S_ + (R - 2048)) * T_ + t] = v;
                } else {
                    CmT[((size_t)b * S_ + (R - 2064)) * T_ + t] = v;
                }
            }
        }
    }
}

// ---------------------------------------------------------------------------
// 256x256 bf16 MFMA GEMM, 8-phase counted-vmcnt schedule (R7-verified:
// QKV ~62 us). mode 2: fused QKV (Q/K heads, V transposed).
// ---------------------------------------------------------------------------
__global__ __launch_bounds__(512, 2) void gemm_mfma256(
    const unsigned short* __restrict__ A, const unsigned short* __restrict__ Bm,
    const float* __restrict__ bias,
    void* __restrict__ outv, void* __restrict__ out2,
    void* __restrict__ out3,
    int M, int N, int K, int lda)
{
    __shared__ __align__(16) unsigned short AS[2][2][8192];
    __shared__ __align__(16) unsigned short BS[2][2][8192];

    const int tid = threadIdx.x;              // 0..511
    const int w = tid >> 6, lane = tid & 63;
    const int lq = lane & 15, lg = lane >> 4;
    const int wm = w >> 2, wn = w & 3;        // 2 x 4 wave grid
    const int mBase = blockIdx.y * 256, nBase = blockIdx.x * 256;

    const int c0 = tid, c1 = tid + 512;
    const int r0 = ((c0 >> 6) << 4) | (c0 & 15), k0l = ((c0 >> 4) & 3) << 3;
    const int r1 = ((c1 >> 6) << 4) | (c1 & 15), k1l = ((c1 >> 4) & 3) << 3;
    const unsigned short* gA0 = A  + (size_t)(mBase + r0) * lda + k0l;
    const unsigned short* gA1 = A  + (size_t)(mBase + r1) * lda + k1l;
    const unsigned short* gB0 = Bm + (size_t)(nBase + r0) * lda + k0l;
    const unsigned short* gB1 = Bm + (size_t)(nBase + r1) * lda + k1l;

    f32x4 acc[8][4];
#pragma unroll
    for (int i = 0; i < 8; ++i)
#pragma unroll
        for (int j = 0; j < 4; ++j) acc[i][j] = (f32x4){0.f, 0.f, 0.f, 0.f};

    #define STG_A(buf_, half_, kb_)                                           \
        do {                                                                  \
            gload16(gA0 + (kb_) + (half_) * 32, &AS[buf_][half_][c0 * 8]);    \
            gload16(gA1 + (kb_) + (half_) * 32, &AS[buf_][half_][c1 * 8]);    \
        } while (0)
    #define STG_B(buf_, half_, kb_)                                           \
        do {                                                                  \
            gload16(gB0 + (kb_) + (half_) * 32, &BS[buf_][half_][c0 * 8]);    \
            gload16(gB1 + (kb_) + (half_) * 32, &BS[buf_][half_][c1 * 8]);    \
        } while (0)
    #define WAITV8() asm volatile("s_waitcnt vmcnt(8)" ::: "memory")
    #define WAITV4() asm volatile("s_waitcnt vmcnt(4)" ::: "memory")
    #define WAITV0() asm volatile("s_waitcnt vmcnt(0)" ::: "memory")

    #define PHASE(buf_, half_, qi_, STAGE_STMT, GATE_STMT)                    \
        do {                                                                  \
            short8 a_[4];                                                     \
            _Pragma("unroll")                                                 \
            for (int i = 0; i < 4; ++i)                                       \
                a_[i] = *(const short8*)&AS[buf_][half_]                      \
                    [((wm * 8 + (qi_) * 4 + i) * 64 + lg * 16 + lq) * 8];     \
            if ((qi_) == 0) {                                                 \
                _Pragma("unroll")                                             \
                for (int j = 0; j < 4; ++j)                                   \
                    bfr[j] = *(const short8*)&BS[buf_][half_]                 \
                        [((wn * 4 + j) * 64 + lg * 16 + lq) * 8];             \
            }                                                                 \
            STAGE_STMT;                                                       \
            __builtin_amdgcn_s_barrier();                                     \
            asm volatile("s_waitcnt lgkmcnt(0)" ::: "memory");                \
            __builtin_amdgcn_s_setprio(1);                                    \
            _Pragma("unroll")                                                 \
            for (int i = 0; i < 4; ++i)                                       \
                _Pragma("unroll")                                             \
                for (int j = 0; j < 4; ++j)                                   \
                    acc[(qi_) * 4 + i][j] =                                   \
                        __builtin_amdgcn_mfma_f32_16x16x32_bf16(              \
                            a_[i], bfr[j], acc[(qi_) * 4 + i][j], 0, 0, 0);   \
            __builtin_amdgcn_s_setprio(0);                                    \
            GATE_STMT;                                                        \
            __builtin_amdgcn_s_barrier();                                     \
        } while (0)

    STG_A(0, 0, 0);
    STG_B(0, 0, 0);
    STG_A(0, 1, 0);
    STG_B(0, 1, 0);
    STG_A(1, 0, 64);
    STG_B(1, 0, 64);
    WAITV8();
    __builtin_amdgcn_s_barrier();

    const int NT = K >> 6;
    for (int kt = 0; kt < NT; ++kt) {
        const int buf = kt & 1, nbuf = buf ^ 1;
        const int kb1 = (kt + 1) << 6, kb2 = (kt + 2) << 6;
        short8 bfr[4];
        PHASE(buf, 0, 0, { if (kt + 1 < NT) STG_A(nbuf, 1, kb1); }, {});
        PHASE(buf, 0, 1, { if (kt + 1 < NT) STG_B(nbuf, 1, kb1); },
              { if (kt < NT - 1) WAITV8(); else WAITV0(); });
        PHASE(buf, 1, 0, { if (kt + 2 < NT) STG_A(buf, 0, kb2); }, {});
        PHASE(buf, 1, 1, { if (kt + 2 < NT) STG_B(buf, 0, kb2); },
              { if (kt < NT - 2) WAITV8();
                else if (kt == NT - 2) WAITV4(); });
    }
    #undef STG_A
    #undef STG_B
    #undef WAITV8
    #undef WAITV4
    #undef WAITV0
    #undef PHASE

    // mode 2: QKV epilogue
    unsigned short* Qb  = (unsigned short*)outv;
    unsigned short* Kb  = (unsigned short*)out2;
    unsigned short* VTb = (unsigned short*)out3;
#pragma unroll
    for (int j = 0; j < 4; ++j) {
        int Cg = nBase + wn * 64 + j * 16 + lq;
        int reg = Cg >> 10, c = Cg & 1023;
        int h = c >> 6, hd = c & 63;
        float bb = bias[Cg];
#pragma unroll
        for (int i = 0; i < 8; ++i) {
            int Rb = mBase + wm * 128 + i * 16 + lg * 4;
#pragma unroll
            for (int r = 0; r < 4; ++r) {
                int R = Rb + r, b = R >> 11, t = R & (T_ - 1);
                unsigned short o = f2bf(acc[i][j][r] + bb);
                if (reg == 0)
                    Qb[(((size_t)(b * H_ + h) * T_ + t) * HD_) + hd] = o;
                else if (reg == 1)
                    Kb[(((size_t)(b * H_ + h) * T_ + t) * HD_) + hd] = o;
                else
                    VTb[(((size_t)(b * H_ + h) * HD_ + hd) * T_) + t] = o;
            }
        }
    }
}

// ---------------------------------------------------------------------------
// Chunked scan, FOLD=4, NCH=32 (R8-verified mapping) + 1-deep register
// prefetch (de-confounded probe: scan was stuck at 550 GB/s with VGPR=32 —
// too few registers to keep the 10 loads/iter in flight; prefetch raises
// landing space so HBM latency hides under the previous iteration's exp/fma).
// ---------------------------------------------------------------------------
__global__ __launch_bounds__(256) void scan_partial(
    const float* __restrict__ xbaseT, const float* __restrict__ deltaT,
    const float* __restrict__ BmT, const float* __restrict__ A_log,
    float4* __restrict__ Pbuf, float4* __restrict__ Lbuf)
{
    const int tid = threadIdx.x;
    const int s4 = tid & 3;
    const int cm = tid >> 2;
    const int cg = blockIdx.x & 15;
    const int k  = (blockIdx.x >> 4) & (NCH - 1);
    const int b  = blockIdx.x >> 9;
    const int c  = cg * 64 + cm;

    float a[4];
#pragma unroll
    for (int j = 0; j < 4; ++j)
        a[j] = -__expf(A_log[c * S_ + s4 * 4 + j]);

    const int tb = k * CHL;
    const float* dp = deltaT + ((size_t)b * C_ + c) * T_ + tb;
    const float* xp = xbaseT + ((size_t)b * C_ + c) * T_ + tb;
    const float* bp = BmT + ((size_t)(b * S_ + s4 * 4)) * T_ + tb;

    float L[4] = {0.f, 0.f, 0.f, 0.f};
    float sumd = 0.f;

    // prefetch t0 = 0
    float4 d4 = *(const float4*)&dp[0];
    float4 x4 = *(const float4*)&xp[0];
    float4 b4[4];
#pragma unroll
    for (int j = 0; j < 4; ++j) b4[j] = *(const float4*)&bp[(size_t)j * T_];

    for (int t0 = 0; t0 < CHL; t0 += 4) {
        const int tn = (t0 + 4 < CHL) ? t0 + 4 : t0;   // uniform, always valid
        float4 d4n = *(const float4*)&dp[tn];
        float4 x4n = *(const float4*)&xp[tn];
        float4 b4n[4];
#pragma unroll
        for (int j = 0; j < 4; ++j)
            b4n[j] = *(const float4*)&bp[(size_t)j * T_ + tn];

        float dv[4] = {d4.x, d4.y, d4.z, d4.w};
        float xv[4] = {x4.x, x4.y, x4.z, x4.w};
        float bv[4][4];
#pragma unroll
        for (int j = 0; j < 4; ++j) {
            bv[j][0] = b4[j].x; bv[j][1] = b4[j].y;
            bv[j][2] = b4[j].z; bv[j][3] = b4[j].w;
        }
#pragma unroll
        for (int q = 0; q < 4; ++q) {
            float u = dv[q] * xv[q];
            sumd += dv[q];
#pragma unroll
            for (int j = 0; j < 4; ++j)
                L[j] = fmaf(__expf(dv[q] * a[j]), L[j], u * bv[j][q]);
        }
        d4 = d4n; x4 = x4n;
#pragma unroll
        for (int j = 0; j < 4; ++j) b4[j] = b4n[j];
    }
    int gid = blockIdx.x * 256 + tid;
    float4 P4 = {__expf(a[0] * sumd), __expf(a[1] * sumd),
                 __expf(a[2] * sumd), __expf(a[3] * sumd)};
    float4 L4 = {L[0], L[1], L[2], L[3]};
    Pbuf[gid] = P4;
    Lbuf[gid] = L4;
}

__global__ __launch_bounds__(256) void scan_final(
    const float* __restrict__ xbaseT, const float* __restrict__ deltaT,
    const float* __restrict__ BmT, const float* __restrict__ CmT,
    const float* __restrict__ A_log, const float4* __restrict__ Pbuf,
    const float4* __restrict__ Lbuf, float* __restrict__ hyb)
{
    const int tid = threadIdx.x;
    const int s4 = tid & 3;
    const int cm = tid >> 2;
    const int cg = blockIdx.x & 15;
    const int k  = (blockIdx.x >> 4) & (NCH - 1);
    const int b  = blockIdx.x >> 9;
    const int c  = cg * 64 + cm;

    float h[4] = {0.f, 0.f, 0.f, 0.f};
    if (k > 0) {
        // prefix combine with 1-deep prefetch (loads independent of h-chain)
        const size_t g0 = (size_t)(((b * NCH) << 4) + cg) * 256 + tid;
        float4 P4 = Pbuf[g0], L4 = Lbuf[g0];
        for (int k2 = 1; k2 < k; ++k2) {
            size_t gn = g0 + (size_t)k2 * 4096;
            float4 P4n = Pbuf[gn], L4n = Lbuf[gn];
            h[0] = fmaf(P4.x, h[0], L4.x);
            h[1] = fmaf(P4.y, h[1], L4.y);
            h[2] = fmaf(P4.z, h[2], L4.z);
            h[3] = fmaf(P4.w, h[3], L4.w);
            P4 = P4n; L4 = L4n;
        }
        h[0] = fmaf(P4.x, h[0], L4.x);
        h[1] = fmaf(P4.y, h[1], L4.y);
        h[2] = fmaf(P4.z, h[2], L4.z);
        h[3] = fmaf(P4.w, h[3], L4.w);
    }

    float a[4];
#pragma unroll
    for (int j = 0; j < 4; ++j)
        a[j] = -__expf(A_log[c * S_ + s4 * 4 + j]);

    const int tb = k * CHL;
    const float* dp = deltaT + ((size_t)b * C_ + c) * T_ + tb;
    const float* xp = xbaseT + ((size_t)b * C_ + c) * T_ + tb;
    const float* bp = BmT + ((size_t)(b * S_ + s4 * 4)) * T_ + tb;
    const float* cp = CmT + ((size_t)(b * S_ + s4 * 4)) * T_ + tb;
    float* hp = hyb + ((size_t)b * T_ + tb) * C_ + c;

    // prefetch t0 = 0
    float4 d4 = *(const float4*)&dp[0];
    float4 x4 = *(const float4*)&xp[0];
    float4 b4[4], c4[4];
#pragma unroll
    for (int j = 0; j < 4; ++j) {
        b4[j] = *(const float4*)&bp[(size_t)j * T_];
        c4[j] = *(const float4*)&cp[(size_t)j * T_];
    }

    for (int t0 = 0; t0 < CHL; t0 += 4) {
        const int tn = (t0 + 4 < CHL) ? t0 + 4 : t0;
        float4 d4n = *(const float4*)&dp[tn];
        float4 x4n = *(const float4*)&xp[tn];
        float4 b4n[4], c4n[4];
#pragma unroll
        for (int j = 0; j < 4; ++j) {
            b4n[j] = *(const float4*)&bp[(size_t)j * T_ + tn];
            c4n[j] = *(const float4*)&cp[(size_t)j * T_ + tn];
        }

        float dv[4] = {d4.x, d4.y, d4.z, d4.w};
        float xv[4] = {x4.x, x4.y, x4.z, x4.w};
        float bv[4][4], cv[4][4];
#pragma unroll
        for (int j = 0; j < 4; ++j) {
            bv[j][0] = b4[j].x; bv[j][1] = b4[j].y;
            bv[j][2] = b4[j].z; bv[j][3] = b4[j].w;
            cv[j][0] = c4[j].x; cv[j][1] = c4[j].y;
            cv[j][2] = c4[j].z; cv[j][3] = c4[j].w;
        }
#pragma unroll
        for (int q = 0; q < 4; ++q) {
            float u = dv[q] * xv[q];
#pragma unroll
            for (int j = 0; j < 4; ++j)
                h[j] = fmaf(__expf(dv[q] * a[j]), h[j], u * bv[j][q]);
            float y = h[0] * cv[0][q];
            y = fmaf(h[1], cv[1][q], y);
            y = fmaf(h[2], cv[2][q], y);
            y = fmaf(h[3], cv[3][q], y);
            y += __shfl_xor(y, 1, 64);
            y += __shfl_xor(y, 2, 64);
            if (s4 == 0) hp[(size_t)(t0 + q) * C_] = xv[q] + y;
        }
        d4 = d4n; x4 = x4n;
#pragma unroll
        for (int j = 0; j < 4; ++j) { b4[j] = b4n[j]; c4[j] = c4n[j]; }
    }
}

// ---------------------------------------------------------------------------
// LayerNorm over C=1024, bf16 output.
// ---------------------------------------------------------------------------
__global__ __launch_bounds__(256) void layernorm_kernel(
    const float* __restrict__ in, const float* __restrict__ g,
    const float* __restrict__ beta, unsigned short* __restrict__ out)
{
    const int row = blockIdx.x;
    const float* rp = in + (size_t)row * C_;
    const int c = threadIdx.x * 4;
    float4 v = *(const float4*)&rp[c];
    float sum = v.x + v.y + v.z + v.w;
    float sq = v.x * v.x + v.y * v.y + v.z * v.z + v.w * v.w;
#pragma unroll
    for (int off = 1; off < 64; off <<= 1) {
        sum += __shfl_xor(sum, off, 64);
        sq += __shfl_xor(sq, off, 64);
    }
    __shared__ float sS[4], sQ[4];
    int wave = threadIdx.x >> 6, lane = threadIdx.x & 63;
    if (lane == 0) { sS[wave] = sum; sQ[wave] = sq; }
    __syncthreads();
    sum = sS[0] + sS[1] + sS[2] + sS[3];
    sq = sQ[0] + sQ[1] + sQ[2] + sQ[3];
    const float mu = sum * (1.f / C_);
    const float var = sq * (1.f / C_) - mu * mu;
    const float rstd = rsqrtf(var + 1e-5f);
    float4 gg = *(const float4*)&g[c];
    float4 bb = *(const float4*)&beta[c];
    ushort4v o;
    o.x = f2bf((v.x - mu) * rstd * gg.x + bb.x);
    o.y = f2bf((v.y - mu) * rstd * gg.y + bb.y);
    o.z = f2bf((v.z - mu) * rstd * gg.z + bb.z);
    o.w = f2bf((v.w - mu) * rstd * gg.w + bb.w);
    *(ushort4v*)&out[(size_t)row * C_ + c] = o;
}

// ---------------------------------------------------------------------------
// MFMA flash attention v2: BK=128, register-prefetch pipeline, ones-column
// row-sum trick, Q fragments in registers. q-tile pair (31-p, p).
// ---------------------------------------------------------------------------
#define BKT 128
#define KP  72
#define VP  136
__global__ __launch_bounds__(256) void attn_mfma(
    const unsigned short* __restrict__ Q, const unsigned short* __restrict__ K,
    const unsigned short* __restrict__ VT, const float* __restrict__ temp,
    unsigned short* __restrict__ out)
{
    __shared__ __align__(16) unsigned short Ks[BKT * KP];
    __shared__ __align__(16) unsigned short Vs[80 * VP];
    __shared__ __align__(16) unsigned short Ps[64 * VP];

    const int tid = threadIdx.x;
    const int w = tid >> 6, lane = tid & 63;
    const int lq = lane & 15, lg = lane >> 4;
    const int p  = blockIdx.x & 15;
    const int bh = blockIdx.x >> 4;
    const int b = bh >> 4, h = bh & 15;

    const float scale = softplus_f(temp[h]) * 0.125f;
    const unsigned short* Qp = Q + (size_t)bh * T_ * HD_;
    const unsigned short* Kp = K + (size_t)bh * T_ * HD_;
    const unsigned short* Vp = VT + (size_t)bh * HD_ * T_;

    {
        int r = 64 + (tid >> 4), o = (tid & 15) * 8;
        ushort8 ones = {0x3f80, 0x3f80, 0x3f80, 0x3f80,
                        0x3f80, 0x3f80, 0x3f80, 0x3f80};
        *(ushort8*)&Vs[r * VP + o] = ones;
    }

    ushort8 kreg[4], vreg[4];
    #define LOADKV(jtv)                                                        \
        do {                                                                   \
            int kb = (jtv) * BKT;                                              \
            _Pragma("unroll")                                                  \
            for (int q2 = 0; q2 < 4; ++q2) {                                   \
                int c = tid + q2 * 256;                                        \
                kreg[q2] = *(const ushort8*)&Kp[(size_t)(kb + (c >> 3)) * HD_  \
                                                + (c & 7) * 8];                \
                vreg[q2] = *(const ushort8*)&Vp[(size_t)(c >> 4) * T_ + kb     \
                                                + (c & 15) * 8];               \
            }                                                                  \
        } while (0)

    for (int half = 0; half < 2; ++half) {
        const int qi = half ? p : (31 - p);
        const int qbase = qi * 64;
        const int nT = (qbase + 64 + BKT - 1) / BKT;

        short8 qf[2];
#pragma unroll
        for (int s = 0; s < 2; ++s)
            qf[s] = *(const short8*)&Qp[(size_t)(qbase + w * 16 + lq) * HD_
                                        + s * 32 + lg * 8];
        LOADKV(0);

        float m_i[4];
        f32x4 o[5];
#pragma unroll
        for (int r = 0; r < 4; ++r) m_i[r] = -INFINITY;
#pragma unroll
        for (int j = 0; j < 5; ++j) o[j] = (f32x4){0.f, 0.f, 0.f, 0.f};

        for (int jt = 0; jt < nT; ++jt) {
            const int kbase = jt * BKT;
            const bool last = (jt == nT - 1);
            __syncthreads();
#pragma unroll
            for (int q2 = 0; q2 < 4; ++q2) {
                int c = tid + q2 * 256;
                *(ushort8*)&Ks[(c >> 3) * KP + (c & 7) * 8] = kreg[q2];
                *(ushort8*)&Vs[(c >> 4) * VP + (c & 15) * 8] = vreg[q2];
            }
            __syncthreads();
            if (jt + 1 < nT) LOADKV(jt + 1);

            f32x4 sacc[8];
#pragma unroll
            for (int j = 0; j < 8; ++j) sacc[j] = (f32x4){0.f, 0.f, 0.f, 0.f};
#pragma unroll
            for (int s = 0; s < 2; ++s) {
#pragma unroll
                for (int j = 0; j < 8; ++j) {
                    short8 kf = *(const short8*)&Ks[(j * 16 + lq) * KP
                                                    + s * 32 + lg * 8];
                    sacc[j] = __builtin_amdgcn_mfma_f32_16x16x32_bf16(
                        qf[s], kf, sacc[j], 0, 0, 0);
                }
            }

#pragma unroll
            for (int r = 0; r < 4; ++r) {
                int qrow = qbase + w * 16 + lg * 4 + r;
                float sv[8];
#pragma unroll
                for (int j = 0; j < 8; ++j) {
                    sv[j] = sacc[j][r] * scale;
                    if (last && (kbase + j * 16 + lq > qrow)) sv[j] = -INFINITY;
                }
                float mx = sv[0];
#pragma unroll
                for (int j = 1; j < 8; ++j) mx = fmaxf(mx, sv[j]);
                mx = fmaxf(mx, __shfl_xor(mx, 1, 64));
                mx = fmaxf(mx, __shfl_xor(mx, 2, 64));
                mx = fmaxf(mx, __shfl_xor(mx, 4, 64));
                mx = fmaxf(mx, __shfl_xor(mx, 8, 64));
                float mnew = fmaxf(m_i[r], mx);
                float alpha = __expf(m_i[r] - mnew);
                m_i[r] = mnew;
#pragma unroll
                for (int j = 0; j < 5; ++j) o[j][r] *= alpha;
#pragma unroll
                for (int j = 0; j < 8; ++j)
                    Ps[(w * 16 + lg * 4 + r) * VP + j * 16 + lq] =
                        f2bf(__expf(sv[j] - mnew));
            }

#pragma unroll
            for (int s2 = 0; s2 < 4; ++s2) {
                short8 pf = *(const short8*)&Ps[(w * 16 + lq) * VP
                                                + s2 * 32 + lg * 8];
#pragma unroll
                for (int j = 0; j < 5; ++j) {
                    short8 vf = *(const short8*)&Vs[(j * 16 + lq) * VP
                                                    + s2 * 32 + lg * 8];
                    o[j] = __builtin_amdgcn_mfma_f32_16x16x32_bf16(
                        pf, vf, o[j], 0, 0, 0);
                }
            }
        }

#pragma unroll
        for (int r = 0; r < 4; ++r) {
            float inv = 1.f / o[4][r];
            int qrow = qbase + w * 16 + lg * 4 + r;
#pragma unroll
            for (int j = 0; j < 4; ++j)
                out[((size_t)(b * T_ + qrow)) * C_ + h * 64 + j * 16 + lq] =
                    f2bf(o[j][r] * inv);
        }
    }
    #undef LOADKV
}

// ---------------------------------------------------------------------------
extern "C" void kernel_launch(void* const* d_in, const int* in_sizes, int n_in,
                              void* d_out, int out_size, void* d_ws, size_t ws_size,
                              hipStream_t stream)
{
    const float* x     = (const float*)d_in[0];
    const float* A_log = (const float*)d_in[1];
    const float* Wd    = (const float*)d_in[2];
    const float* bd    = (const float*)d_in[3];
    const float* WB    = (const float*)d_in[4];
    const float* WC    = (const float*)d_in[5];
    const float* Wq    = (const float*)d_in[6];
    const float* bq    = (const float*)d_in[7];
    const float* Wk    = (const float*)d_in[8];
    const float* bk    = (const float*)d_in[9];
    const float* Wv    = (const float*)d_in[10];
    const float* bv    = (const float*)d_in[11];
    const float* Wx    = (const float*)d_in[12];
    const float* bx    = (const float*)d_in[13];
    const float* Wo    = (const float*)d_in[14];
    const float* bo    = (const float*)d_in[15];
    const float* ln_g  = (const float*)d_in[16];
    const float* ln_b  = (const float*)d_in[17];
    const float* temp  = (const float*)d_in[18];

    char* wsb = (char*)d_ws;
    const size_t MB = 1024 * 1024;
    const size_t HMB = 512 * 1024;
    // Workspace (timeline-disjoint; NCH=32 — R8-verified layout):
    //  [0,8):      xb (dead after projT) -> Pbuf [0,4) + Lbuf [4,8)
    //              -> hybrid (layernorm)
    //  [8,12.5):   Astack + biasPD/biasQKV
    //  [12.5,18.5): WqkvT
    //  [18.5,34.5): deltaT  ([18.5,20.5) head doubles as WoT post-attention)
    //  [20.5,28.5): Qb (QKV, after scan)
    //  [28.5,36.5): Kb
    //  [34.5,50.5): xbaseT
    //  [36.5,44.5): VTb
    //  [44.5,52.5): attnO
    //  [50.5,66.5): hyb
    //  [66.5,67):  BmT/CmT
    unsigned short* xb      = (unsigned short*)(wsb);
    float4* Pbuf            = (float4*)(wsb);
    float4* Lbuf            = (float4*)(wsb + 4 * MB);
    unsigned short* hybrid  = (unsigned short*)(wsb);
    unsigned short* Astack  = (unsigned short*)(wsb + 8 * MB);
    float* biasPD           = (float*)(wsb + 8 * MB + (size_t)2176 * 2048);
    float* biasQKV          = biasPD + 2176;
    unsigned short* WqkvT   = (unsigned short*)(wsb + 12 * MB + HMB);
    unsigned short* WoT     = (unsigned short*)(wsb + 18 * MB + HMB);
    float* deltaT           = (float*)(wsb + 18 * MB + HMB);
    float* xbaseT           = (float*)(wsb + 34 * MB + HMB);
    float* hyb              = (float*)(wsb + 50 * MB + HMB);
    float* BmT              = (float*)(wsb + 66 * MB + HMB);
    float* CmT              = BmT + (size_t)B_ * S_ * T_;
    unsigned short* Qb      = (unsigned short*)(wsb + 20 * MB + HMB);
    unsigned short* Kb      = (unsigned short*)(wsb + 28 * MB + HMB);
    unsigned short* VTb     = (unsigned short*)(wsb + 36 * MB + HMB);
    unsigned short* attnO   = (unsigned short*)(wsb + 44 * MB + HMB);

    // ---- prep ----
    cast_bf16<<<4096, 256, 0, stream>>>(x, xb, (B_ * T_ * C_) / 4);
    wtrans_multi<<<dim3(32, 32, 5), 256, 0, stream>>>(Wx, Wd, Wq, Wk, Wv,
                                                      Astack, WqkvT);
    prep_misc<<<149, 256, 0, stream>>>(WB, WC, bx, bd, bq, bk, bv,
                                       Astack, biasPD, biasQKV);

    // ---- fused projection-T GEMM (hybrid 128x256, 272 blocks) ----
    gemm_projT<<<dim3(16, 17, 1), 512, 0, stream>>>(
        Astack, xb, biasPD, xbaseT, deltaT, BmT, CmT,
        1024, 1024);

    // ---- chunk-parallel scan (FOLD=4, NCH=32 -> 1024 blocks) ----
    const int scanBlocks = B_ * NCH * (C_ / 64);   // 1024
    scan_partial<<<scanBlocks, 256, 0, stream>>>(xbaseT, deltaT, BmT, A_log,
                                                 Pbuf, Lbuf);
    scan_final<<<scanBlocks, 256, 0, stream>>>(xbaseT, deltaT, BmT, CmT, A_log,
                                               Pbuf, Lbuf, hyb);

    // ---- layernorm ----
    layernorm_kernel<<<B_ * T_, 256, 0, stream>>>(hyb, ln_g, ln_b, hybrid);

    // ---- fused QKV GEMM (256^2 8-phase, R7-verified) ----
    gemm_mfma256<<<dim3(12, 16, 1), 512, 0, stream>>>(
        hybrid, WqkvT, biasQKV, Qb, Kb, VTb,
        4096, 3072, 1024, 1024);

    // ---- attention ----
    attn_mfma<<<B_ * H_ * 16, 256, 0, stream>>>(Qb, Kb, VTb, temp, attnO);

    // ---- Wo transpose + single-pass GEMM with fused bias -> d_out ----
    wtrans<<<dim3(32, 32), 256, 0, stream>>>(Wo, WoT);
    gemm_mfma<<<dim3(8, 32, 1), 256, 0, stream>>>(
        attnO, WoT, bo, d_out,
        4096, 1024, 1024, 1024);
}

// Round 12
// 408.194 us; speedup vs baseline: 1.1552x; 1.1249x over previous
//
#include <hip/hip_runtime.h>
#include <math.h>

#define B_  2
#define T_  2048
#define C_  1024
#define H_  16
#define S_  16
#define HD_ 64
#define NCH 32
#define CHL 64   /* T_/NCH */

typedef short  short8  __attribute__((ext_vector_type(8)));
typedef unsigned short ushort8 __attribute__((ext_vector_type(8)));
typedef unsigned short ushort4v __attribute__((ext_vector_type(4)));
typedef float  f32x4   __attribute__((ext_vector_type(4)));

__device__ __forceinline__ float softplus_f(float v) {
    return fmaxf(v, 0.f) + log1pf(__expf(-fabsf(v)));
}

__device__ __forceinline__ unsigned short f2bf(float x) {
    unsigned u = __float_as_uint(x);
    u += 0x7fffu + ((u >> 16) & 1u);
    return (unsigned short)(u >> 16);
}

// async global -> LDS, 16B per lane. LDS dest = wave-uniform base + lane*16.
__device__ __forceinline__ void gload16(const unsigned short* g,
                                        unsigned short* l)
{
    __builtin_amdgcn_global_load_lds(
        (const __attribute__((address_space(1))) unsigned int*)g,
        (__attribute__((address_space(3))) unsigned int*)l, 16, 0, 0);
}

// ---------------------------------------------------------------------------
// cast fp32 -> bf16 (vectorized), n4 = n/4
// ---------------------------------------------------------------------------
__global__ __launch_bounds__(256) void cast_bf16(const float* __restrict__ in,
                                                 unsigned short* __restrict__ out,
                                                 int n4)
{
    int i = blockIdx.x * 256 + threadIdx.x;
    if (i >= n4) return;
    float4 v = ((const float4*)in)[i];
    ushort4v o = {f2bf(v.x), f2bf(v.y), f2bf(v.z), f2bf(v.w)};
    ((ushort4v*)out)[i] = o;
}

// ---------------------------------------------------------------------------
// transpose-cast: W (1024 x 1024 fp32) -> WT (1024 x 1024 bf16, transposed)
// ---------------------------------------------------------------------------
__device__ __forceinline__ void wtrans_body(const float* __restrict__ W,
                                            unsigned short* __restrict__ WT,
                                            int bx, int by, int tid)
{
    __shared__ float t[32][33];
    const int n0 = bx * 32, k0 = by * 32;
    const int tx = tid & 31, ty = tid >> 5;
#pragma unroll
    for (int p = 0; p < 4; ++p)
        t[ty + p * 8][tx] = W[(size_t)(k0 + ty + p * 8) * C_ + n0 + tx];
    __syncthreads();
#pragma unroll
    for (int p = 0; p < 4; ++p)
        WT[(size_t)(n0 + ty + p * 8) * C_ + k0 + tx] = f2bf(t[tx][ty + p * 8]);
}

__global__ __launch_bounds__(256) void wtrans(const float* __restrict__ W,
                                              unsigned short* __restrict__ WT)
{
    wtrans_body(W, WT, blockIdx.x, blockIdx.y, threadIdx.x);
}

// z: 0 Wx->Astack, 1 Wd->Astack+1024 rows, 2 Wq->Wqkv, 3 Wk->+1024, 4 Wv->+2048
__global__ __launch_bounds__(256) void wtrans_multi(
    const float* __restrict__ Wx, const float* __restrict__ Wd,
    const float* __restrict__ Wq, const float* __restrict__ Wk,
    const float* __restrict__ Wv,
    unsigned short* __restrict__ Astack, unsigned short* __restrict__ Wqkv)
{
    const float* src;
    unsigned short* dst;
    switch (blockIdx.z) {
        case 0: src = Wx; dst = Astack; break;
        case 1: src = Wd; dst = Astack + (size_t)1024 * 1024; break;
        case 2: src = Wq; dst = Wqkv; break;
        case 3: src = Wk; dst = Wqkv + (size_t)1024 * 1024; break;
        default: src = Wv; dst = Wqkv + (size_t)2048 * 1024; break;
    }
    wtrans_body(src, dst, blockIdx.x, blockIdx.y, threadIdx.x);
}

// ---------------------------------------------------------------------------
// misc prep: WB/WC transposed into Astack rows 2048..2079 + stacked biases
// ---------------------------------------------------------------------------
__global__ __launch_bounds__(256) void prep_misc(
    const float* __restrict__ WB, const float* __restrict__ WC,
    const float* __restrict__ bx, const float* __restrict__ bd,
    const float* __restrict__ bq, const float* __restrict__ bk,
    const float* __restrict__ bv,
    unsigned short* __restrict__ Astack, float* __restrict__ biasPD,
    float* __restrict__ biasQKV)
{
    int gid = blockIdx.x * 256 + threadIdx.x;
    if (gid < 32768) {
        int w = gid >> 14, rem = gid & 16383;
        int s = rem >> 10, k = rem & 1023;
        const float* src = w ? WC : WB;
        Astack[(size_t)(2048 + w * 16 + s) * 1024 + k] = f2bf(src[k * 16 + s]);
    } else {
        int id = gid - 32768;
        if (id < 2176) {
            biasPD[id] = id < 1024 ? bx[id] : (id < 2048 ? bd[id - 1024] : 0.f);
        } else {
            int id2 = id - 2176;
            if (id2 < 3072)
                biasQKV[id2] = id2 < 1024 ? bq[id2]
                             : (id2 < 2048 ? bk[id2 - 1024] : bv[id2 - 2048]);
        }
    }
}

// ---------------------------------------------------------------------------
// bf16 MFMA GEMM: 128x128 tile, 4-buffer counted-vmcnt pipeline (R2-verified).
// mode 0: direct fp32 out with bias (Wo projection -> d_out)
// ---------------------------------------------------------------------------
__global__ __launch_bounds__(256) void gemm_mfma(
    const unsigned short* __restrict__ A, const unsigned short* __restrict__ Bm,
    const float* __restrict__ bias,
    void* __restrict__ outv,
    int M, int N, int K, int lda)
{
    __shared__ __align__(16) unsigned short As[4][4096];
    __shared__ __align__(16) unsigned short Bs[4][4096];

    const int tid = threadIdx.x;
    const int w = tid >> 6, lane = tid & 63;
    const int lq = lane & 15, lg = lane >> 4;
    const int wm = w >> 1, wn = w & 1;
    const int mBase = blockIdx.y * 128, nBase = blockIdx.x * 128;

    const int c0 = tid, c1 = tid + 256;
    const int rA0 = ((c0 >> 6) << 4) + (c0 & 15), kO0 = ((c0 >> 4) & 3) << 3;
    const int rA1 = ((c1 >> 6) << 4) + (c1 & 15), kO1 = ((c1 >> 4) & 3) << 3;

    const int wL0 = w * 512;
    const int wL1 = 2048 + w * 512;

    f32x4 acc[4][4];
#pragma unroll
    for (int i = 0; i < 4; ++i)
#pragma unroll
        for (int j = 0; j < 4; ++j) acc[i][j] = (f32x4){0.f, 0.f, 0.f, 0.f};

    const unsigned short* ga0 = A  + (size_t)(mBase + rA0) * lda + kO0;
    const unsigned short* ga1 = A  + (size_t)(mBase + rA1) * lda + kO1;
    const unsigned short* gb0 = Bm + (size_t)(nBase + rA0) * lda + kO0;
    const unsigned short* gb1 = Bm + (size_t)(nBase + rA1) * lda + kO1;

    #define STAGE(bufv, k0v)                               \
        do {                                               \
            gload16(ga0 + (k0v), &As[bufv][wL0]);          \
            gload16(ga1 + (k0v), &As[bufv][wL1]);          \
            gload16(gb0 + (k0v), &Bs[bufv][wL0]);          \
            gload16(gb1 + (k0v), &Bs[bufv][wL1]);          \
        } while (0)
    #define COMPUTE(bufv)                                                       \
        do {                                                                    \
            short8 a[4], b[4];                                                  \
            _Pragma("unroll")                                                   \
            for (int i = 0; i < 4; ++i)                                         \
                a[i] = *(const short8*)&As[bufv][((wm * 4 + i) * 64 + lg * 16 + lq) * 8]; \
            _Pragma("unroll")                                                   \
            for (int j = 0; j < 4; ++j)                                         \
                b[j] = *(const short8*)&Bs[bufv][((wn * 4 + j) * 64 + lg * 16 + lq) * 8]; \
            _Pragma("unroll")                                                   \
            for (int i = 0; i < 4; ++i)                                         \
                _Pragma("unroll")                                               \
                for (int j = 0; j < 4; ++j)                                     \
                    acc[i][j] = __builtin_amdgcn_mfma_f32_16x16x32_bf16(        \
                        a[i], b[j], acc[i][j], 0, 0, 0);                        \
        } while (0)
    #define WAITV4() asm volatile("s_waitcnt vmcnt(4)" ::: "memory")
    #define WAITV0() asm volatile("s_waitcnt vmcnt(0)" ::: "memory")
    #define LGKM0()  asm volatile("s_waitcnt lgkmcnt(0)" ::: "memory")
    #define STEP(cbuf, kt)                                          \
        do {                                                        \
            if ((kt) + 32 < K) WAITV4(); else WAITV0();             \
            LGKM0();                                                \
            __builtin_amdgcn_s_barrier();                           \
            if ((kt) + 64 < K) STAGE(((cbuf) + 2) & 3, (kt) + 64);  \
            COMPUTE(cbuf);                                          \
        } while (0)

    STAGE(0, 0);
    STAGE(1, 32);

    for (int k0 = 0; k0 < K; k0 += 128) {
        STEP(0, k0);
        STEP(1, k0 + 32);
        STEP(2, k0 + 64);
        STEP(3, k0 + 96);
    }
    #undef STAGE
    #undef COMPUTE
    #undef WAITV4
    #undef WAITV0
    #undef LGKM0
    #undef STEP

    // direct fp32 output with bias over N columns (Wo projection)
    float* O = (float*)outv;
#pragma unroll
    for (int j = 0; j < 4; ++j) {
        int Cg = nBase + wn * 64 + j * 16 + lq;
        float bb = bias[Cg];
#pragma unroll
        for (int i = 0; i < 4; ++i) {
            int Rb = mBase + wm * 64 + i * 16 + lg * 4;
#pragma unroll
            for (int r = 0; r < 4; ++r)
                O[(size_t)(Rb + r) * N + Cg] = acc[i][j][r] + bb;
        }
    }
}

// ---------------------------------------------------------------------------
// projT hybrid GEMM: BM=128, BN=256, BK=64, 512 thr = 8 waves (2M x 4N).
// Counted-vmcnt 2-phase-per-K-tile schedule, 272 blocks. (R8-verified.)
// ---------------------------------------------------------------------------
__global__ __launch_bounds__(512, 2) void gemm_projT(
    const unsigned short* __restrict__ A, const unsigned short* __restrict__ Bm,
    const float* __restrict__ bias,
    float* __restrict__ xbaseT, float* __restrict__ deltaT,
    float* __restrict__ BmT, float* __restrict__ CmT,
    int K, int lda)
{
    __shared__ __align__(16) unsigned short AS[2][2][4096];   // 128 x 32
    __shared__ __align__(16) unsigned short BS[2][2][8192];   // 256 x 32

    const int tid = threadIdx.x;              // 0..511
    const int w = tid >> 6, lane = tid & 63;
    const int lq = lane & 15, lg = lane >> 4;
    const int wm = w >> 2, wn = w & 3;        // 2M x 4N wave grid
    const int mBase = blockIdx.y * 128, nBase = blockIdx.x * 256;

    const int rA = ((tid >> 6) << 4) | (tid & 15);
    const int kA = ((tid >> 4) & 3) << 3;
    const unsigned short* gA = A + (size_t)(mBase + rA) * lda + kA;
    const int eA = tid * 8;
    const int c0 = tid, c1 = tid + 512;
    const int rB0 = ((c0 >> 6) << 4) | (c0 & 15), kB0 = ((c0 >> 4) & 3) << 3;
    const int rB1 = ((c1 >> 6) << 4) | (c1 & 15), kB1 = ((c1 >> 4) & 3) << 3;
    const unsigned short* gB0 = Bm + (size_t)(nBase + rB0) * lda + kB0;
    const unsigned short* gB1 = Bm + (size_t)(nBase + rB1) * lda + kB1;

    f32x4 acc[4][4];
#pragma unroll
    for (int i = 0; i < 4; ++i)
#pragma unroll
        for (int j = 0; j < 4; ++j) acc[i][j] = (f32x4){0.f, 0.f, 0.f, 0.f};

    #define STG(buf_, half_, kb_)                                             \
        do {                                                                  \
            gload16(gA  + (kb_) + (half_) * 32, &AS[buf_][half_][eA]);        \
            gload16(gB0 + (kb_) + (half_) * 32, &BS[buf_][half_][c0 * 8]);    \
            gload16(gB1 + (kb_) + (half_) * 32, &BS[buf_][half_][c1 * 8]);    \
        } while (0)
    #define WAITV6() asm volatile("s_waitcnt vmcnt(6)" ::: "memory")
    #define WAITV3() asm volatile("s_waitcnt vmcnt(3)" ::: "memory")
    #define WAITV0() asm volatile("s_waitcnt vmcnt(0)" ::: "memory")

    #define PHASE(buf_, half_, STAGE_STMT, GATE_STMT)                         \
        do {                                                                  \
            short8 a_[4], b_[4];                                              \
            _Pragma("unroll")                                                 \
            for (int i = 0; i < 4; ++i)                                       \
                a_[i] = *(const short8*)&AS[buf_][half_]                      \
                    [((wm * 4 + i) * 64 + lg * 16 + lq) * 8];                 \
            _Pragma("unroll")                                                 \
            for (int j = 0; j < 4; ++j)                                       \
                b_[j] = *(const short8*)&BS[buf_][half_]                      \
                    [((wn * 4 + j) * 64 + lg * 16 + lq) * 8];                 \
            STAGE_STMT;                                                       \
            __builtin_amdgcn_s_barrier();                                     \
            asm volatile("s_waitcnt lgkmcnt(0)" ::: "memory");                \
            __builtin_amdgcn_s_setprio(1);                                    \
            _Pragma("unroll")                                                 \
            for (int i = 0; i < 4; ++i)                                       \
                _Pragma("unroll")                                             \
                for (int j = 0; j < 4; ++j)                                   \
                    acc[i][j] = __builtin_amdgcn_mfma_f32_16x16x32_bf16(      \
                        a_[i], b_[j], acc[i][j], 0, 0, 0);                    \
            __builtin_amdgcn_s_setprio(0);                                    \
            GATE_STMT;                                                        \
            __builtin_amdgcn_s_barrier();                                     \
        } while (0)

    STG(0, 0, 0);
    STG(0, 1, 0);
    STG(1, 0, 64);
    WAITV6();
    __builtin_amdgcn_s_barrier();

    const int NT = K >> 6;                    // 16
    for (int kt = 0; kt < NT; ++kt) {
        const int buf = kt & 1, nbuf = buf ^ 1;
        const int kb1 = (kt + 1) << 6, kb2 = (kt + 2) << 6;
        PHASE(buf, 0, { if (kt + 1 < NT) STG(nbuf, 1, kb1); },
              { if (kt < NT - 1) WAITV6(); else WAITV3(); });
        PHASE(buf, 1, { if (kt + 2 < NT) STG(buf, 0, kb2); },
              { if (kt < NT - 2) WAITV6();
                else if (kt == NT - 2) WAITV3(); else WAITV0(); });
    }
    #undef STG
    #undef WAITV6
    #undef WAITV3
    #undef WAITV0
    #undef PHASE

#pragma unroll
    for (int i = 0; i < 4; ++i) {
        int Rb = mBase + wm * 64 + i * 16 + lg * 4;
        if (Rb >= 2080) continue;
        float bb[4];
#pragma unroll
        for (int r = 0; r < 4; ++r) bb[r] = bias[Rb + r];
#pragma unroll
        for (int j = 0; j < 4; ++j) {
            int Cg = nBase + wn * 64 + j * 16 + lq;
            int b = Cg >> 11, t = Cg & (T_ - 1);
#pragma unroll
            for (int r = 0; r < 4; ++r) {
                int R = Rb + r;
                float v = acc[i][j][r] + bb[r];
                if (Rb < 1024) {
                    xbaseT[((size_t)b * C_ + R) * T_ + t] = v;
                } else if (Rb < 2048) {
                    deltaT[((size_t)b * C_ + (R - 1024)) * T_ + t] =
                        softplus_f(v);
                } else if (Rb < 2064) {
                    BmT[((size_t)b * S_ + (R - 2048)) * T_ + t] = v;
                } else {
                    CmT[((size_t)b * S_ + (R - 2064)) * T_ + t] = v;
                }
            }
        }
    }
}

// ---------------------------------------------------------------------------
// 256x256 bf16 MFMA GEMM, 8-phase counted-vmcnt schedule (R7-verified:
// QKV ~62 us). mode 2: fused QKV (Q/K heads, V transposed).
// ---------------------------------------------------------------------------
__global__ __launch_bounds__(512, 2) void gemm_mfma256(
    const unsigned short* __restrict__ A, const unsigned short* __restrict__ Bm,
    const float* __restrict__ bias,
    void* __restrict__ outv, void* __restrict__ out2,
    void* __restrict__ out3,
    int M, int N, int K, int lda)
{
    __shared__ __align__(16) unsigned short AS[2][2][8192];
    __shared__ __align__(16) unsigned short BS[2][2][8192];

    const int tid = threadIdx.x;              // 0..511
    const int w = tid >> 6, lane = tid & 63;
    const int lq = lane & 15, lg = lane >> 4;
    const int wm = w >> 2, wn = w & 3;        // 2 x 4 wave grid
    const int mBase = blockIdx.y * 256, nBase = blockIdx.x * 256;

    const int c0 = tid, c1 = tid + 512;
    const int r0 = ((c0 >> 6) << 4) | (c0 & 15), k0l = ((c0 >> 4) & 3) << 3;
    const int r1 = ((c1 >> 6) << 4) | (c1 & 15), k1l = ((c1 >> 4) & 3) << 3;
    const unsigned short* gA0 = A  + (size_t)(mBase + r0) * lda + k0l;
    const unsigned short* gA1 = A  + (size_t)(mBase + r1) * lda + k1l;
    const unsigned short* gB0 = Bm + (size_t)(nBase + r0) * lda + k0l;
    const unsigned short* gB1 = Bm + (size_t)(nBase + r1) * lda + k1l;

    f32x4 acc[8][4];
#pragma unroll
    for (int i = 0; i < 8; ++i)
#pragma unroll
        for (int j = 0; j < 4; ++j) acc[i][j] = (f32x4){0.f, 0.f, 0.f, 0.f};

    #define STG_A(buf_, half_, kb_)                                           \
        do {                                                                  \
            gload16(gA0 + (kb_) + (half_) * 32, &AS[buf_][half_][c0 * 8]);    \
            gload16(gA1 + (kb_) + (half_) * 32, &AS[buf_][half_][c1 * 8]);    \
        } while (0)
    #define STG_B(buf_, half_, kb_)                                           \
        do {                                                                  \
            gload16(gB0 + (kb_) + (half_) * 32, &BS[buf_][half_][c0 * 8]);    \
            gload16(gB1 + (kb_) + (half_) * 32, &BS[buf_][half_][c1 * 8]);    \
        } while (0)
    #define WAITV8() asm volatile("s_waitcnt vmcnt(8)" ::: "memory")
    #define WAITV4() asm volatile("s_waitcnt vmcnt(4)" ::: "memory")
    #define WAITV0() asm volatile("s_waitcnt vmcnt(0)" ::: "memory")

    #define PHASE(buf_, half_, qi_, STAGE_STMT, GATE_STMT)                    \
        do {                                                                  \
            short8 a_[4];                                                     \
            _Pragma("unroll")                                                 \
            for (int i = 0; i < 4; ++i)                                       \
                a_[i] = *(const short8*)&AS[buf_][half_]                      \
                    [((wm * 8 + (qi_) * 4 + i) * 64 + lg * 16 + lq) * 8];     \
            if ((qi_) == 0) {                                                 \
                _Pragma("unroll")                                             \
                for (int j = 0; j < 4; ++j)                                   \
                    bfr[j] = *(const short8*)&BS[buf_][half_]                 \
                        [((wn * 4 + j) * 64 + lg * 16 + lq) * 8];             \
            }                                                                 \
            STAGE_STMT;                                                       \
            __builtin_amdgcn_s_barrier();                                     \
            asm volatile("s_waitcnt lgkmcnt(0)" ::: "memory");                \
            __builtin_amdgcn_s_setprio(1);                                    \
            _Pragma("unroll")                                                 \
            for (int i = 0; i < 4; ++i)                                       \
                _Pragma("unroll")                                             \
                for (int j = 0; j < 4; ++j)                                   \
                    acc[(qi_) * 4 + i][j] =                                   \
                        __builtin_amdgcn_mfma_f32_16x16x32_bf16(              \
                            a_[i], bfr[j], acc[(qi_) * 4 + i][j], 0, 0, 0);   \
            __builtin_amdgcn_s_setprio(0);                                    \
            GATE_STMT;                                                        \
            __builtin_amdgcn_s_barrier();                                     \
        } while (0)

    STG_A(0, 0, 0);
    STG_B(0, 0, 0);
    STG_A(0, 1, 0);
    STG_B(0, 1, 0);
    STG_A(1, 0, 64);
    STG_B(1, 0, 64);
    WAITV8();
    __builtin_amdgcn_s_barrier();

    const int NT = K >> 6;
    for (int kt = 0; kt < NT; ++kt) {
        const int buf = kt & 1, nbuf = buf ^ 1;
        const int kb1 = (kt + 1) << 6, kb2 = (kt + 2) << 6;
        short8 bfr[4];
        PHASE(buf, 0, 0, { if (kt + 1 < NT) STG_A(nbuf, 1, kb1); }, {});
        PHASE(buf, 0, 1, { if (kt + 1 < NT) STG_B(nbuf, 1, kb1); },
              { if (kt < NT - 1) WAITV8(); else WAITV0(); });
        PHASE(buf, 1, 0, { if (kt + 2 < NT) STG_A(buf, 0, kb2); }, {});
        PHASE(buf, 1, 1, { if (kt + 2 < NT) STG_B(buf, 0, kb2); },
              { if (kt < NT - 2) WAITV8();
                else if (kt == NT - 2) WAITV4(); });
    }
    #undef STG_A
    #undef STG_B
    #undef WAITV8
    #undef WAITV4
    #undef WAITV0
    #undef PHASE

    // mode 2: QKV epilogue
    unsigned short* Qb  = (unsigned short*)outv;
    unsigned short* Kb  = (unsigned short*)out2;
    unsigned short* VTb = (unsigned short*)out3;
#pragma unroll
    for (int j = 0; j < 4; ++j) {
        int Cg = nBase + wn * 64 + j * 16 + lq;
        int reg = Cg >> 10, c = Cg & 1023;
        int h = c >> 6, hd = c & 63;
        float bb = bias[Cg];
#pragma unroll
        for (int i = 0; i < 8; ++i) {
            int Rb = mBase + wm * 128 + i * 16 + lg * 4;
#pragma unroll
            for (int r = 0; r < 4; ++r) {
                int R = Rb + r, b = R >> 11, t = R & (T_ - 1);
                unsigned short o = f2bf(acc[i][j][r] + bb);
                if (reg == 0)
                    Qb[(((size_t)(b * H_ + h) * T_ + t) * HD_) + hd] = o;
                else if (reg == 1)
                    Kb[(((size_t)(b * H_ + h) * T_ + t) * HD_) + hd] = o;
                else
                    VTb[(((size_t)(b * H_ + h) * HD_ + hd) * T_) + t] = o;
            }
        }
    }
}

// ---------------------------------------------------------------------------
// Restructured chunked scan: ONE THREAD = ONE CHANNEL, all 16 s-states in
// registers; B^T/C^T tiles staged once per block into LDS as [t][s]
// (channel-invariant -> broadcast reads). Removes the old 4x redundant d/x
// loads, all cross-lane shuffles, and converts the serial exp->fma recurrence
// into 16 independent streams (in-thread ILP hides VALU+LDS latency).
// Grid: B*NCH*4 = 256 blocks x 256 threads (channel group cg = bid&3).
// Pbuf/Lbuf: [(b*NCH+k)*1024 + c] * 4 float4 (P and L, 16 floats each).
// ---------------------------------------------------------------------------
__global__ __launch_bounds__(256) void scan_partial(
    const float* __restrict__ xbaseT, const float* __restrict__ deltaT,
    const float* __restrict__ BmT, const float* __restrict__ A_log,
    float4* __restrict__ Pbuf, float4* __restrict__ Lbuf)
{
    __shared__ float bs[CHL * 16];   // [t][s]
    const int tid = threadIdx.x;
    const int cg = blockIdx.x & 3;
    const int k  = (blockIdx.x >> 2) & (NCH - 1);
    const int b  = blockIdx.x >> 7;
    const int c  = cg * 256 + tid;
    const int tb = k * CHL;

    // stage B^T[t][s] (transposed from BmT[s][t]); coalesced over t
    {
        int t0 = tid & 63, sg = (tid >> 6) << 2;
#pragma unroll
        for (int j = 0; j < 4; ++j)
            bs[t0 * 16 + sg + j] =
                BmT[((size_t)(b * S_ + sg + j)) * T_ + tb + t0];
    }
    float a[16];
#pragma unroll
    for (int sq = 0; sq < 4; ++sq) {
        float4 a4 = *(const float4*)&A_log[(size_t)c * S_ + sq * 4];
        a[sq * 4 + 0] = -__expf(a4.x);
        a[sq * 4 + 1] = -__expf(a4.y);
        a[sq * 4 + 2] = -__expf(a4.z);
        a[sq * 4 + 3] = -__expf(a4.w);
    }
    __syncthreads();

    const float* dp = deltaT + ((size_t)b * C_ + c) * T_ + tb;
    const float* xp = xbaseT + ((size_t)b * C_ + c) * T_ + tb;

    float h[16];
#pragma unroll
    for (int s = 0; s < 16; ++s) h[s] = 0.f;
    float sumd = 0.f;

    float4 d4 = *(const float4*)&dp[0];
    float4 x4 = *(const float4*)&xp[0];
    for (int t0 = 0; t0 < CHL; t0 += 4) {
        const int tn = (t0 + 4 < CHL) ? t0 + 4 : t0;
        float4 d4n = *(const float4*)&dp[tn];
        float4 x4n = *(const float4*)&xp[tn];
        float dv[4] = {d4.x, d4.y, d4.z, d4.w};
        float xv[4] = {x4.x, x4.y, x4.z, x4.w};
#pragma unroll
        for (int q = 0; q < 4; ++q) {
            float u = dv[q] * xv[q];
            sumd += dv[q];
            float bv[16];
#pragma unroll
            for (int sq = 0; sq < 4; ++sq) {
                float4 b4 = *(const float4*)&bs[(t0 + q) * 16 + sq * 4];
                bv[sq * 4 + 0] = b4.x; bv[sq * 4 + 1] = b4.y;
                bv[sq * 4 + 2] = b4.z; bv[sq * 4 + 3] = b4.w;
            }
#pragma unroll
            for (int s = 0; s < 16; ++s)
                h[s] = fmaf(__expf(dv[q] * a[s]), h[s], u * bv[s]);
        }
        d4 = d4n; x4 = x4n;
    }

    const size_t base = ((size_t)((b * NCH + k) << 10) + c) * 4;
#pragma unroll
    for (int sq = 0; sq < 4; ++sq) {
        float4 P4 = {__expf(a[sq * 4 + 0] * sumd), __expf(a[sq * 4 + 1] * sumd),
                     __expf(a[sq * 4 + 2] * sumd), __expf(a[sq * 4 + 3] * sumd)};
        float4 L4 = {h[sq * 4 + 0], h[sq * 4 + 1],
                     h[sq * 4 + 2], h[sq * 4 + 3]};
        Pbuf[base + sq] = P4;
        Lbuf[base + sq] = L4;
    }
}

__global__ __launch_bounds__(256) void scan_final(
    const float* __restrict__ xbaseT, const float* __restrict__ deltaT,
    const float* __restrict__ BmT, const float* __restrict__ CmT,
    const float* __restrict__ A_log, const float4* __restrict__ Pbuf,
    const float4* __restrict__ Lbuf, float* __restrict__ hyb)
{
    __shared__ float bs[CHL * 16];   // [t][s]
    __shared__ float cs[CHL * 16];   // [t][s]
    const int tid = threadIdx.x;
    const int cg = blockIdx.x & 3;
    const int k  = (blockIdx.x >> 2) & (NCH - 1);
    const int b  = blockIdx.x >> 7;
    const int c  = cg * 256 + tid;
    const int tb = k * CHL;

    {
        int t0 = tid & 63, sg = (tid >> 6) << 2;
#pragma unroll
        for (int j = 0; j < 4; ++j) {
            bs[t0 * 16 + sg + j] =
                BmT[((size_t)(b * S_ + sg + j)) * T_ + tb + t0];
            cs[t0 * 16 + sg + j] =
                CmT[((size_t)(b * S_ + sg + j)) * T_ + tb + t0];
        }
    }
    float a[16];
#pragma unroll
    for (int sq = 0; sq < 4; ++sq) {
        float4 a4 = *(const float4*)&A_log[(size_t)c * S_ + sq * 4];
        a[sq * 4 + 0] = -__expf(a4.x);
        a[sq * 4 + 1] = -__expf(a4.y);
        a[sq * 4 + 2] = -__expf(a4.z);
        a[sq * 4 + 3] = -__expf(a4.w);
    }

    // prefix combine over chunks 0..k-1 (sequential by construction)
    float h[16];
#pragma unroll
    for (int s = 0; s < 16; ++s) h[s] = 0.f;
    for (int k2 = 0; k2 < k; ++k2) {
        const size_t b2 = ((size_t)((b * NCH + k2) << 10) + c) * 4;
#pragma unroll
        for (int sq = 0; sq < 4; ++sq) {
            float4 P4 = Pbuf[b2 + sq];
            float4 L4 = Lbuf[b2 + sq];
            h[sq * 4 + 0] = fmaf(P4.x, h[sq * 4 + 0], L4.x);
            h[sq * 4 + 1] = fmaf(P4.y, h[sq * 4 + 1], L4.y);
            h[sq * 4 + 2] = fmaf(P4.z, h[sq * 4 + 2], L4.z);
            h[sq * 4 + 3] = fmaf(P4.w, h[sq * 4 + 3], L4.w);
        }
    }
    __syncthreads();

    const float* dp = deltaT + ((size_t)b * C_ + c) * T_ + tb;
    const float* xp = xbaseT + ((size_t)b * C_ + c) * T_ + tb;
    float* hp = hyb + ((size_t)b * T_ + tb) * C_ + c;

    float4 d4 = *(const float4*)&dp[0];
    float4 x4 = *(const float4*)&xp[0];
    for (int t0 = 0; t0 < CHL; t0 += 4) {
        const int tn = (t0 + 4 < CHL) ? t0 + 4 : t0;
        float4 d4n = *(const float4*)&dp[tn];
        float4 x4n = *(const float4*)&xp[tn];
        float dv[4] = {d4.x, d4.y, d4.z, d4.w};
        float xv[4] = {x4.x, x4.y, x4.z, x4.w};
#pragma unroll
        for (int q = 0; q < 4; ++q) {
            float u = dv[q] * xv[q];
            float bv[16], cv[16];
#pragma unroll
            for (int sq = 0; sq < 4; ++sq) {
                float4 b4 = *(const float4*)&bs[(t0 + q) * 16 + sq * 4];
                float4 c4 = *(const float4*)&cs[(t0 + q) * 16 + sq * 4];
                bv[sq * 4 + 0] = b4.x; bv[sq * 4 + 1] = b4.y;
                bv[sq * 4 + 2] = b4.z; bv[sq * 4 + 3] = b4.w;
                cv[sq * 4 + 0] = c4.x; cv[sq * 4 + 1] = c4.y;
                cv[sq * 4 + 2] = c4.z; cv[sq * 4 + 3] = c4.w;
            }
#pragma unroll
            for (int s = 0; s < 16; ++s)
                h[s] = fmaf(__expf(dv[q] * a[s]), h[s], u * bv[s]);
            float y0 = 0.f, y1 = 0.f, y2 = 0.f, y3 = 0.f;
#pragma unroll
            for (int sq = 0; sq < 4; ++sq) {
                y0 = fmaf(h[sq * 4 + 0], cv[sq * 4 + 0], y0);
                y1 = fmaf(h[sq * 4 + 1], cv[sq * 4 + 1], y1);
                y2 = fmaf(h[sq * 4 + 2], cv[sq * 4 + 2], y2);
                y3 = fmaf(h[sq * 4 + 3], cv[sq * 4 + 3], y3);
            }
            hp[(size_t)(t0 + q) * C_] = xv[q] + ((y0 + y1) + (y2 + y3));
        }
        d4 = d4n; x4 = x4n;
    }
}

// ---------------------------------------------------------------------------
// LayerNorm over C=1024, bf16 output.
// ---------------------------------------------------------------------------
__global__ __launch_bounds__(256) void layernorm_kernel(
    const float* __restrict__ in, const float* __restrict__ g,
    const float* __restrict__ beta, unsigned short* __restrict__ out)
{
    const int row = blockIdx.x;
    const float* rp = in + (size_t)row * C_;
    const int c = threadIdx.x * 4;
    float4 v = *(const float4*)&rp[c];
    float sum = v.x + v.y + v.z + v.w;
    float sq = v.x * v.x + v.y * v.y + v.z * v.z + v.w * v.w;
#pragma unroll
    for (int off = 1; off < 64; off <<= 1) {
        sum += __shfl_xor(sum, off, 64);
        sq += __shfl_xor(sq, off, 64);
    }
    __shared__ float sS[4], sQ[4];
    int wave = threadIdx.x >> 6, lane = threadIdx.x & 63;
    if (lane == 0) { sS[wave] = sum; sQ[wave] = sq; }
    __syncthreads();
    sum = sS[0] + sS[1] + sS[2] + sS[3];
    sq = sQ[0] + sQ[1] + sQ[2] + sQ[3];
    const float mu = sum * (1.f / C_);
    const float var = sq * (1.f / C_) - mu * mu;
    const float rstd = rsqrtf(var + 1e-5f);
    float4 gg = *(const float4*)&g[c];
    float4 bb = *(const float4*)&beta[c];
    ushort4v o;
    o.x = f2bf((v.x - mu) * rstd * gg.x + bb.x);
    o.y = f2bf((v.y - mu) * rstd * gg.y + bb.y);
    o.z = f2bf((v.z - mu) * rstd * gg.z + bb.z);
    o.w = f2bf((v.w - mu) * rstd * gg.w + bb.w);
    *(ushort4v*)&out[(size_t)row * C_ + c] = o;
}

// ---------------------------------------------------------------------------
// MFMA flash attention v2: BK=128, register-prefetch pipeline, ones-column
// row-sum trick, Q fragments in registers. q-tile pair (31-p, p).
// ---------------------------------------------------------------------------
#define BKT 128
#define KP  72
#define VP  136
__global__ __launch_bounds__(256) void attn_mfma(
    const unsigned short* __restrict__ Q, const unsigned short* __restrict__ K,
    const unsigned short* __restrict__ VT, const float* __restrict__ temp,
    unsigned short* __restrict__ out)
{
    __shared__ __align__(16) unsigned short Ks[BKT * KP];
    __shared__ __align__(16) unsigned short Vs[80 * VP];
    __shared__ __align__(16) unsigned short Ps[64 * VP];

    const int tid = threadIdx.x;
    const int w = tid >> 6, lane = tid & 63;
    const int lq = lane & 15, lg = lane >> 4;
    const int p  = blockIdx.x & 15;
    const int bh = blockIdx.x >> 4;
    const int b = bh >> 4, h = bh & 15;

    const float scale = softplus_f(temp[h]) * 0.125f;
    const unsigned short* Qp = Q + (size_t)bh * T_ * HD_;
    const unsigned short* Kp = K + (size_t)bh * T_ * HD_;
    const unsigned short* Vp = VT + (size_t)bh * HD_ * T_;

    {
        int r = 64 + (tid >> 4), o = (tid & 15) * 8;
        ushort8 ones = {0x3f80, 0x3f80, 0x3f80, 0x3f80,
                        0x3f80, 0x3f80, 0x3f80, 0x3f80};
        *(ushort8*)&Vs[r * VP + o] = ones;
    }

    ushort8 kreg[4], vreg[4];
    #define LOADKV(jtv)                                                        \
        do {                                                                   \
            int kb = (jtv) * BKT;                                              \
            _Pragma("unroll")                                                  \
            for (int q2 = 0; q2 < 4; ++q2) {                                   \
                int c = tid + q2 * 256;                                        \
                kreg[q2] = *(const ushort8*)&Kp[(size_t)(kb + (c >> 3)) * HD_  \
                                                + (c & 7) * 8];                \
                vreg[q2] = *(const ushort8*)&Vp[(size_t)(c >> 4) * T_ + kb     \
                                                + (c & 15) * 8];               \
            }                                                                  \
        } while (0)

    for (int half = 0; half < 2; ++half) {
        const int qi = half ? p : (31 - p);
        const int qbase = qi * 64;
        const int nT = (qbase + 64 + BKT - 1) / BKT;

        short8 qf[2];
#pragma unroll
        for (int s = 0; s < 2; ++s)
            qf[s] = *(const short8*)&Qp[(size_t)(qbase + w * 16 + lq) * HD_
                                        + s * 32 + lg * 8];
        LOADKV(0);

        float m_i[4];
        f32x4 o[5];
#pragma unroll
        for (int r = 0; r < 4; ++r) m_i[r] = -INFINITY;
#pragma unroll
        for (int j = 0; j < 5; ++j) o[j] = (f32x4){0.f, 0.f, 0.f, 0.f};

        for (int jt = 0; jt < nT; ++jt) {
            const int kbase = jt * BKT;
            const bool last = (jt == nT - 1);
            __syncthreads();
#pragma unroll
            for (int q2 = 0; q2 < 4; ++q2) {
                int c = tid + q2 * 256;
                *(ushort8*)&Ks[(c >> 3) * KP + (c & 7) * 8] = kreg[q2];
                *(ushort8*)&Vs[(c >> 4) * VP + (c & 15) * 8] = vreg[q2];
            }
            __syncthreads();
            if (jt + 1 < nT) LOADKV(jt + 1);

            f32x4 sacc[8];
#pragma unroll
            for (int j = 0; j < 8; ++j) sacc[j] = (f32x4){0.f, 0.f, 0.f, 0.f};
#pragma unroll
            for (int s = 0; s < 2; ++s) {
#pragma unroll
                for (int j = 0; j < 8; ++j) {
                    short8 kf = *(const short8*)&Ks[(j * 16 + lq) * KP
                                                    + s * 32 + lg * 8];
                    sacc[j] = __builtin_amdgcn_mfma_f32_16x16x32_bf16(
                        qf[s], kf, sacc[j], 0, 0, 0);
                }
            }

#pragma unroll
            for (int r = 0; r < 4; ++r) {
                int qrow = qbase + w * 16 + lg * 4 + r;
                float sv[8];
#pragma unroll
                for (int j = 0; j < 8; ++j) {
                    sv[j] = sacc[j][r] * scale;
                    if (last && (kbase + j * 16 + lq > qrow)) sv[j] = -INFINITY;
                }
                float mx = sv[0];
#pragma unroll
                for (int j = 1; j < 8; ++j) mx = fmaxf(mx, sv[j]);
                mx = fmaxf(mx, __shfl_xor(mx, 1, 64));
                mx = fmaxf(mx, __shfl_xor(mx, 2, 64));
                mx = fmaxf(mx, __shfl_xor(mx, 4, 64));
                mx = fmaxf(mx, __shfl_xor(mx, 8, 64));
                float mnew = fmaxf(m_i[r], mx);
                float alpha = __expf(m_i[r] - mnew);
                m_i[r] = mnew;
#pragma unroll
                for (int j = 0; j < 5; ++j) o[j][r] *= alpha;
#pragma unroll
                for (int j = 0; j < 8; ++j)
                    Ps[(w * 16 + lg * 4 + r) * VP + j * 16 + lq] =
                        f2bf(__expf(sv[j] - mnew));
            }

#pragma unroll
            for (int s2 = 0; s2 < 4; ++s2) {
                short8 pf = *(const short8*)&Ps[(w * 16 + lq) * VP
                                                + s2 * 32 + lg * 8];
#pragma unroll
                for (int j = 0; j < 5; ++j) {
                    short8 vf = *(const short8*)&Vs[(j * 16 + lq) * VP
                                                    + s2 * 32 + lg * 8];
                    o[j] = __builtin_amdgcn_mfma_f32_16x16x32_bf16(
                        pf, vf, o[j], 0, 0, 0);
                }
            }
        }

#pragma unroll
        for (int r = 0; r < 4; ++r) {
            float inv = 1.f / o[4][r];
            int qrow = qbase + w * 16 + lg * 4 + r;
#pragma unroll
            for (int j = 0; j < 4; ++j)
                out[((size_t)(b * T_ + qrow)) * C_ + h * 64 + j * 16 + lq] =
                    f2bf(o[j][r] * inv);
        }
    }
    #undef LOADKV
}

// ---------------------------------------------------------------------------
extern "C" void kernel_launch(void* const* d_in, const int* in_sizes, int n_in,
                              void* d_out, int out_size, void* d_ws, size_t ws_size,
                              hipStream_t stream)
{
    const float* x     = (const float*)d_in[0];
    const float* A_log = (const float*)d_in[1];
    const float* Wd    = (const float*)d_in[2];
    const float* bd    = (const float*)d_in[3];
    const float* WB    = (const float*)d_in[4];
    const float* WC    = (const float*)d_in[5];
    const float* Wq    = (const float*)d_in[6];
    const float* bq    = (const float*)d_in[7];
    const float* Wk    = (const float*)d_in[8];
    const float* bk    = (const float*)d_in[9];
    const float* Wv    = (const float*)d_in[10];
    const float* bv    = (const float*)d_in[11];
    const float* Wx    = (const float*)d_in[12];
    const float* bx    = (const float*)d_in[13];
    const float* Wo    = (const float*)d_in[14];
    const float* bo    = (const float*)d_in[15];
    const float* ln_g  = (const float*)d_in[16];
    const float* ln_b  = (const float*)d_in[17];
    const float* temp  = (const float*)d_in[18];

    char* wsb = (char*)d_ws;
    const size_t MB = 1024 * 1024;
    const size_t HMB = 512 * 1024;
    // Workspace (timeline-disjoint; NCH=32 — R8-verified layout):
    //  [0,8):      xb (dead after projT) -> Pbuf [0,4) + Lbuf [4,8)
    //              -> hybrid (layernorm)
    //  [8,12.5):   Astack + biasPD/biasQKV
    //  [12.5,18.5): WqkvT
    //  [18.5,34.5): deltaT  ([18.5,20.5) head doubles as WoT post-attention)
    //  [20.5,28.5): Qb (QKV, after scan)
    //  [28.5,36.5): Kb
    //  [34.5,50.5): xbaseT
    //  [36.5,44.5): VTb
    //  [44.5,52.5): attnO
    //  [50.5,66.5): hyb
    //  [66.5,67):  BmT/CmT
    unsigned short* xb      = (unsigned short*)(wsb);
    float4* Pbuf            = (float4*)(wsb);
    float4* Lbuf            = (float4*)(wsb + 4 * MB);
    unsigned short* hybrid  = (unsigned short*)(wsb);
    unsigned short* Astack  = (unsigned short*)(wsb + 8 * MB);
    float* biasPD           = (float*)(wsb + 8 * MB + (size_t)2176 * 2048);
    float* biasQKV          = biasPD + 2176;
    unsigned short* WqkvT   = (unsigned short*)(wsb + 12 * MB + HMB);
    unsigned short* WoT     = (unsigned short*)(wsb + 18 * MB + HMB);
    float* deltaT           = (float*)(wsb + 18 * MB + HMB);
    float* xbaseT           = (float*)(wsb + 34 * MB + HMB);
    float* hyb              = (float*)(wsb + 50 * MB + HMB);
    float* BmT              = (float*)(wsb + 66 * MB + HMB);
    float* CmT              = BmT + (size_t)B_ * S_ * T_;
    unsigned short* Qb      = (unsigned short*)(wsb + 20 * MB + HMB);
    unsigned short* Kb      = (unsigned short*)(wsb + 28 * MB + HMB);
    unsigned short* VTb     = (unsigned short*)(wsb + 36 * MB + HMB);
    unsigned short* attnO   = (unsigned short*)(wsb + 44 * MB + HMB);

    // ---- prep ----
    cast_bf16<<<4096, 256, 0, stream>>>(x, xb, (B_ * T_ * C_) / 4);
    wtrans_multi<<<dim3(32, 32, 5), 256, 0, stream>>>(Wx, Wd, Wq, Wk, Wv,
                                                      Astack, WqkvT);
    prep_misc<<<149, 256, 0, stream>>>(WB, WC, bx, bd, bq, bk, bv,
                                       Astack, biasPD, biasQKV);

    // ---- fused projection-T GEMM (hybrid 128x256, 272 blocks) ----
    gemm_projT<<<dim3(16, 17, 1), 512, 0, stream>>>(
        Astack, xb, biasPD, xbaseT, deltaT, BmT, CmT,
        1024, 1024);

    // ---- chunk-parallel scan (channel-per-thread, s-in-registers) ----
    const int scanBlocks = B_ * NCH * 4;   // 256 blocks x 256 threads
    scan_partial<<<scanBlocks, 256, 0, stream>>>(xbaseT, deltaT, BmT, A_log,
                                                 Pbuf, Lbuf);
    scan_final<<<scanBlocks, 256, 0, stream>>>(xbaseT, deltaT, BmT, CmT, A_log,
                                               Pbuf, Lbuf, hyb);

    // ---- layernorm ----
    layernorm_kernel<<<B_ * T_, 256, 0, stream>>>(hyb, ln_g, ln_b, hybrid);

    // ---- fused QKV GEMM (256^2 8-phase, R7-verified) ----
    gemm_mfma256<<<dim3(12, 16, 1), 512, 0, stream>>>(
        hybrid, WqkvT, biasQKV, Qb, Kb, VTb,
        4096, 3072, 1024, 1024);

    // ---- attention ----
    attn_mfma<<<B_ * H_ * 16, 256, 0, stream>>>(Qb, Kb, VTb, temp, attnO);

    // ---- Wo transpose + single-pass GEMM with fused bias -> d_out ----
    wtrans<<<dim3(32, 32), 256, 0, stream>>>(Wo, WoT);
    gemm_mfma<<<dim3(8, 32, 1), 256, 0, stream>>>(
        attnO, WoT, bo, d_out,
        4096, 1024, 1024, 1024);
}

// Round 13
// 406.787 us; speedup vs baseline: 1.1592x; 1.0035x over previous
//
#include <hip/hip_runtime.h>
#include <math.h>

#define B_  2
#define T_  2048
#define C_  1024
#define H_  16
#define S_  16
#define HD_ 64
#define NCH 32
#define CHL 64   /* T_/NCH */

typedef short  short8  __attribute__((ext_vector_type(8)));
typedef unsigned short ushort8 __attribute__((ext_vector_type(8)));
typedef unsigned short ushort4v __attribute__((ext_vector_type(4)));
typedef float  f32x4   __attribute__((ext_vector_type(4)));

__device__ __forceinline__ float softplus_f(float v) {
    return fmaxf(v, 0.f) + log1pf(__expf(-fabsf(v)));
}

__device__ __forceinline__ unsigned short f2bf(float x) {
    unsigned u = __float_as_uint(x);
    u += 0x7fffu + ((u >> 16) & 1u);
    return (unsigned short)(u >> 16);
}

__device__ __forceinline__ float bf2f(unsigned short u) {
    return __uint_as_float(((unsigned)u) << 16);
}

// async global -> LDS, 16B per lane. LDS dest = wave-uniform base + lane*16.
__device__ __forceinline__ void gload16(const unsigned short* g,
                                        unsigned short* l)
{
    __builtin_amdgcn_global_load_lds(
        (const __attribute__((address_space(1))) unsigned int*)g,
        (__attribute__((address_space(3))) unsigned int*)l, 16, 0, 0);
}

// ---------------------------------------------------------------------------
// cast fp32 -> bf16 (vectorized), n4 = n/4
// ---------------------------------------------------------------------------
__global__ __launch_bounds__(256) void cast_bf16(const float* __restrict__ in,
                                                 unsigned short* __restrict__ out,
                                                 int n4)
{
    int i = blockIdx.x * 256 + threadIdx.x;
    if (i >= n4) return;
    float4 v = ((const float4*)in)[i];
    ushort4v o = {f2bf(v.x), f2bf(v.y), f2bf(v.z), f2bf(v.w)};
    ((ushort4v*)out)[i] = o;
}

// ---------------------------------------------------------------------------
// transpose-cast: W (1024 x 1024 fp32) -> WT (1024 x 1024 bf16, transposed)
// ---------------------------------------------------------------------------
__device__ __forceinline__ void wtrans_body(const float* __restrict__ W,
                                            unsigned short* __restrict__ WT,
                                            int bx, int by, int tid)
{
    __shared__ float t[32][33];
    const int n0 = bx * 32, k0 = by * 32;
    const int tx = tid & 31, ty = tid >> 5;
#pragma unroll
    for (int p = 0; p < 4; ++p)
        t[ty + p * 8][tx] = W[(size_t)(k0 + ty + p * 8) * C_ + n0 + tx];
    __syncthreads();
#pragma unroll
    for (int p = 0; p < 4; ++p)
        WT[(size_t)(n0 + ty + p * 8) * C_ + k0 + tx] = f2bf(t[tx][ty + p * 8]);
}

__global__ __launch_bounds__(256) void wtrans(const float* __restrict__ W,
                                              unsigned short* __restrict__ WT)
{
    wtrans_body(W, WT, blockIdx.x, blockIdx.y, threadIdx.x);
}

// z: 0 Wx->Astack, 1 Wd->Astack+1024 rows, 2 Wq->Wqkv, 3 Wk->+1024, 4 Wv->+2048
__global__ __launch_bounds__(256) void wtrans_multi(
    const float* __restrict__ Wx, const float* __restrict__ Wd,
    const float* __restrict__ Wq, const float* __restrict__ Wk,
    const float* __restrict__ Wv,
    unsigned short* __restrict__ Astack, unsigned short* __restrict__ Wqkv)
{
    const float* src;
    unsigned short* dst;
    switch (blockIdx.z) {
        case 0: src = Wx; dst = Astack; break;
        case 1: src = Wd; dst = Astack + (size_t)1024 * 1024; break;
        case 2: src = Wq; dst = Wqkv; break;
        case 3: src = Wk; dst = Wqkv + (size_t)1024 * 1024; break;
        default: src = Wv; dst = Wqkv + (size_t)2048 * 1024; break;
    }
    wtrans_body(src, dst, blockIdx.x, blockIdx.y, threadIdx.x);
}

// ---------------------------------------------------------------------------
// misc prep: WB/WC transposed into Astack rows 2048..2079 + stacked biases
// ---------------------------------------------------------------------------
__global__ __launch_bounds__(256) void prep_misc(
    const float* __restrict__ WB, const float* __restrict__ WC,
    const float* __restrict__ bx, const float* __restrict__ bd,
    const float* __restrict__ bq, const float* __restrict__ bk,
    const float* __restrict__ bv,
    unsigned short* __restrict__ Astack, float* __restrict__ biasPD,
    float* __restrict__ biasQKV)
{
    int gid = blockIdx.x * 256 + threadIdx.x;
    if (gid < 32768) {
        int w = gid >> 14, rem = gid & 16383;
        int s = rem >> 10, k = rem & 1023;
        const float* src = w ? WC : WB;
        Astack[(size_t)(2048 + w * 16 + s) * 1024 + k] = f2bf(src[k * 16 + s]);
    } else {
        int id = gid - 32768;
        if (id < 2176) {
            biasPD[id] = id < 1024 ? bx[id] : (id < 2048 ? bd[id - 1024] : 0.f);
        } else {
            int id2 = id - 2176;
            if (id2 < 3072)
                biasQKV[id2] = id2 < 1024 ? bq[id2]
                             : (id2 < 2048 ? bk[id2 - 1024] : bv[id2 - 2048]);
        }
    }
}

// ---------------------------------------------------------------------------
// bf16 MFMA GEMM: 128x128 tile, 4-buffer counted-vmcnt pipeline (R2-verified).
// mode 0: direct fp32 out with bias (Wo projection -> d_out)
// ---------------------------------------------------------------------------
__global__ __launch_bounds__(256) void gemm_mfma(
    const unsigned short* __restrict__ A, const unsigned short* __restrict__ Bm,
    const float* __restrict__ bias,
    void* __restrict__ outv,
    int M, int N, int K, int lda)
{
    __shared__ __align__(16) unsigned short As[4][4096];
    __shared__ __align__(16) unsigned short Bs[4][4096];

    const int tid = threadIdx.x;
    const int w = tid >> 6, lane = tid & 63;
    const int lq = lane & 15, lg = lane >> 4;
    const int wm = w >> 1, wn = w & 1;
    const int mBase = blockIdx.y * 128, nBase = blockIdx.x * 128;

    const int c0 = tid, c1 = tid + 256;
    const int rA0 = ((c0 >> 6) << 4) + (c0 & 15), kO0 = ((c0 >> 4) & 3) << 3;
    const int rA1 = ((c1 >> 6) << 4) + (c1 & 15), kO1 = ((c1 >> 4) & 3) << 3;

    const int wL0 = w * 512;
    const int wL1 = 2048 + w * 512;

    f32x4 acc[4][4];
#pragma unroll
    for (int i = 0; i < 4; ++i)
#pragma unroll
        for (int j = 0; j < 4; ++j) acc[i][j] = (f32x4){0.f, 0.f, 0.f, 0.f};

    const unsigned short* ga0 = A  + (size_t)(mBase + rA0) * lda + kO0;
    const unsigned short* ga1 = A  + (size_t)(mBase + rA1) * lda + kO1;
    const unsigned short* gb0 = Bm + (size_t)(nBase + rA0) * lda + kO0;
    const unsigned short* gb1 = Bm + (size_t)(nBase + rA1) * lda + kO1;

    #define STAGE(bufv, k0v)                               \
        do {                                               \
            gload16(ga0 + (k0v), &As[bufv][wL0]);          \
            gload16(ga1 + (k0v), &As[bufv][wL1]);          \
            gload16(gb0 + (k0v), &Bs[bufv][wL0]);          \
            gload16(gb1 + (k0v), &Bs[bufv][wL1]);          \
        } while (0)
    #define COMPUTE(bufv)                                                       \
        do {                                                                    \
            short8 a[4], b[4];                                                  \
            _Pragma("unroll")                                                   \
            for (int i = 0; i < 4; ++i)                                         \
                a[i] = *(const short8*)&As[bufv][((wm * 4 + i) * 64 + lg * 16 + lq) * 8]; \
            _Pragma("unroll")                                                   \
            for (int j = 0; j < 4; ++j)                                         \
                b[j] = *(const short8*)&Bs[bufv][((wn * 4 + j) * 64 + lg * 16 + lq) * 8]; \
            _Pragma("unroll")                                                   \
            for (int i = 0; i < 4; ++i)                                         \
                _Pragma("unroll")                                               \
                for (int j = 0; j < 4; ++j)                                     \
                    acc[i][j] = __builtin_amdgcn_mfma_f32_16x16x32_bf16(        \
                        a[i], b[j], acc[i][j], 0, 0, 0);                        \
        } while (0)
    #define WAITV4() asm volatile("s_waitcnt vmcnt(4)" ::: "memory")
    #define WAITV0() asm volatile("s_waitcnt vmcnt(0)" ::: "memory")
    #define LGKM0()  asm volatile("s_waitcnt lgkmcnt(0)" ::: "memory")
    #define STEP(cbuf, kt)                                          \
        do {                                                        \
            if ((kt) + 32 < K) WAITV4(); else WAITV0();             \
            LGKM0();                                                \
            __builtin_amdgcn_s_barrier();                           \
            if ((kt) + 64 < K) STAGE(((cbuf) + 2) & 3, (kt) + 64);  \
            COMPUTE(cbuf);                                          \
        } while (0)

    STAGE(0, 0);
    STAGE(1, 32);

    for (int k0 = 0; k0 < K; k0 += 128) {
        STEP(0, k0);
        STEP(1, k0 + 32);
        STEP(2, k0 + 64);
        STEP(3, k0 + 96);
    }
    #undef STAGE
    #undef COMPUTE
    #undef WAITV4
    #undef WAITV0
    #undef LGKM0
    #undef STEP

    // direct fp32 output with bias over N columns (Wo projection)
    float* O = (float*)outv;
#pragma unroll
    for (int j = 0; j < 4; ++j) {
        int Cg = nBase + wn * 64 + j * 16 + lq;
        float bb = bias[Cg];
#pragma unroll
        for (int i = 0; i < 4; ++i) {
            int Rb = mBase + wm * 64 + i * 16 + lg * 4;
#pragma unroll
            for (int r = 0; r < 4; ++r)
                O[(size_t)(Rb + r) * N + Cg] = acc[i][j][r] + bb;
        }
    }
}

// ---------------------------------------------------------------------------
// projT hybrid GEMM: BM=128, BN=256, BK=64, 512 thr = 8 waves (2M x 4N).
// Counted-vmcnt 2-phase-per-K-tile schedule, 272 blocks. (R8-verified.)
// xbaseT/deltaT now stored bf16 (halves epilogue WRITE + scan FETCH).
// ---------------------------------------------------------------------------
__global__ __launch_bounds__(512, 2) void gemm_projT(
    const unsigned short* __restrict__ A, const unsigned short* __restrict__ Bm,
    const float* __restrict__ bias,
    unsigned short* __restrict__ xbaseT, unsigned short* __restrict__ deltaT,
    float* __restrict__ BmT, float* __restrict__ CmT,
    int K, int lda)
{
    __shared__ __align__(16) unsigned short AS[2][2][4096];   // 128 x 32
    __shared__ __align__(16) unsigned short BS[2][2][8192];   // 256 x 32

    const int tid = threadIdx.x;              // 0..511
    const int w = tid >> 6, lane = tid & 63;
    const int lq = lane & 15, lg = lane >> 4;
    const int wm = w >> 2, wn = w & 3;        // 2M x 4N wave grid
    const int mBase = blockIdx.y * 128, nBase = blockIdx.x * 256;

    const int rA = ((tid >> 6) << 4) | (tid & 15);
    const int kA = ((tid >> 4) & 3) << 3;
    const unsigned short* gA = A + (size_t)(mBase + rA) * lda + kA;
    const int eA = tid * 8;
    const int c0 = tid, c1 = tid + 512;
    const int rB0 = ((c0 >> 6) << 4) | (c0 & 15), kB0 = ((c0 >> 4) & 3) << 3;
    const int rB1 = ((c1 >> 6) << 4) | (c1 & 15), kB1 = ((c1 >> 4) & 3) << 3;
    const unsigned short* gB0 = Bm + (size_t)(nBase + rB0) * lda + kB0;
    const unsigned short* gB1 = Bm + (size_t)(nBase + rB1) * lda + kB1;

    f32x4 acc[4][4];
#pragma unroll
    for (int i = 0; i < 4; ++i)
#pragma unroll
        for (int j = 0; j < 4; ++j) acc[i][j] = (f32x4){0.f, 0.f, 0.f, 0.f};

    #define STG(buf_, half_, kb_)                                             \
        do {                                                                  \
            gload16(gA  + (kb_) + (half_) * 32, &AS[buf_][half_][eA]);        \
            gload16(gB0 + (kb_) + (half_) * 32, &BS[buf_][half_][c0 * 8]);    \
            gload16(gB1 + (kb_) + (half_) * 32, &BS[buf_][half_][c1 * 8]);    \
        } while (0)
    #define WAITV6() asm volatile("s_waitcnt vmcnt(6)" ::: "memory")
    #define WAITV3() asm volatile("s_waitcnt vmcnt(3)" ::: "memory")
    #define WAITV0() asm volatile("s_waitcnt vmcnt(0)" ::: "memory")

    #define PHASE(buf_, half_, STAGE_STMT, GATE_STMT)                         \
        do {                                                                  \
            short8 a_[4], b_[4];                                              \
            _Pragma("unroll")                                                 \
            for (int i = 0; i < 4; ++i)                                       \
                a_[i] = *(const short8*)&AS[buf_][half_]                      \
                    [((wm * 4 + i) * 64 + lg * 16 + lq) * 8];                 \
            _Pragma("unroll")                                                 \
            for (int j = 0; j < 4; ++j)                                       \
                b_[j] = *(const short8*)&BS[buf_][half_]                      \
                    [((wn * 4 + j) * 64 + lg * 16 + lq) * 8];                 \
            STAGE_STMT;                                                       \
            __builtin_amdgcn_s_barrier();                                     \
            asm volatile("s_waitcnt lgkmcnt(0)" ::: "memory");                \
            __builtin_amdgcn_s_setprio(1);                                    \
            _Pragma("unroll")                                                 \
            for (int i = 0; i < 4; ++i)                                       \
                _Pragma("unroll")                                             \
                for (int j = 0; j < 4; ++j)                                   \
                    acc[i][j] = __builtin_amdgcn_mfma_f32_16x16x32_bf16(      \
                        a_[i], b_[j], acc[i][j], 0, 0, 0);                    \
            __builtin_amdgcn_s_setprio(0);                                    \
            GATE_STMT;                                                        \
            __builtin_amdgcn_s_barrier();                                     \
        } while (0)

    STG(0, 0, 0);
    STG(0, 1, 0);
    STG(1, 0, 64);
    WAITV6();
    __builtin_amdgcn_s_barrier();

    const int NT = K >> 6;                    // 16
    for (int kt = 0; kt < NT; ++kt) {
        const int buf = kt & 1, nbuf = buf ^ 1;
        const int kb1 = (kt + 1) << 6, kb2 = (kt + 2) << 6;
        PHASE(buf, 0, { if (kt + 1 < NT) STG(nbuf, 1, kb1); },
              { if (kt < NT - 1) WAITV6(); else WAITV3(); });
        PHASE(buf, 1, { if (kt + 2 < NT) STG(buf, 0, kb2); },
              { if (kt < NT - 2) WAITV6();
                else if (kt == NT - 2) WAITV3(); else WAITV0(); });
    }
    #undef STG
    #undef WAITV6
    #undef WAITV3
    #undef WAITV0
    #undef PHASE

#pragma unroll
    for (int i = 0; i < 4; ++i) {
        int Rb = mBase + wm * 64 + i * 16 + lg * 4;
        if (Rb >= 2080) continue;
        float bb[4];
#pragma unroll
        for (int r = 0; r < 4; ++r) bb[r] = bias[Rb + r];
#pragma unroll
        for (int j = 0; j < 4; ++j) {
            int Cg = nBase + wn * 64 + j * 16 + lq;
            int b = Cg >> 11, t = Cg & (T_ - 1);
#pragma unroll
            for (int r = 0; r < 4; ++r) {
                int R = Rb + r;
                float v = acc[i][j][r] + bb[r];
                if (Rb < 1024) {
                    xbaseT[((size_t)b * C_ + R) * T_ + t] = f2bf(v);
                } else if (Rb < 2048) {
                    deltaT[((size_t)b * C_ + (R - 1024)) * T_ + t] =
                        f2bf(softplus_f(v));
                } else if (Rb < 2064) {
                    BmT[((size_t)b * S_ + (R - 2048)) * T_ + t] = v;
                } else {
                    CmT[((size_t)b * S_ + (R - 2064)) * T_ + t] = v;
                }
            }
        }
    }
}

// ---------------------------------------------------------------------------
// 256x256 bf16 MFMA GEMM, 8-phase counted-vmcnt schedule (R7-verified:
// QKV ~62 us). mode 2: fused QKV (Q/K heads, V transposed).
// ---------------------------------------------------------------------------
__global__ __launch_bounds__(512, 2) void gemm_mfma256(
    const unsigned short* __restrict__ A, const unsigned short* __restrict__ Bm,
    const float* __restrict__ bias,
    void* __restrict__ outv, void* __restrict__ out2,
    void* __restrict__ out3,
    int M, int N, int K, int lda)
{
    __shared__ __align__(16) unsigned short AS[2][2][8192];
    __shared__ __align__(16) unsigned short BS[2][2][8192];

    const int tid = threadIdx.x;              // 0..511
    const int w = tid >> 6, lane = tid & 63;
    const int lq = lane & 15, lg = lane >> 4;
    const int wm = w >> 2, wn = w & 3;        // 2 x 4 wave grid
    const int mBase = blockIdx.y * 256, nBase = blockIdx.x * 256;

    const int c0 = tid, c1 = tid + 512;
    const int r0 = ((c0 >> 6) << 4) | (c0 & 15), k0l = ((c0 >> 4) & 3) << 3;
    const int r1 = ((c1 >> 6) << 4) | (c1 & 15), k1l = ((c1 >> 4) & 3) << 3;
    const unsigned short* gA0 = A  + (size_t)(mBase + r0) * lda + k0l;
    const unsigned short* gA1 = A  + (size_t)(mBase + r1) * lda + k1l;
    const unsigned short* gB0 = Bm + (size_t)(nBase + r0) * lda + k0l;
    const unsigned short* gB1 = Bm + (size_t)(nBase + r1) * lda + k1l;

    f32x4 acc[8][4];
#pragma unroll
    for (int i = 0; i < 8; ++i)
#pragma unroll
        for (int j = 0; j < 4; ++j) acc[i][j] = (f32x4){0.f, 0.f, 0.f, 0.f};

    #define STG_A(buf_, half_, kb_)                                           \
        do {                                                                  \
            gload16(gA0 + (kb_) + (half_) * 32, &AS[buf_][half_][c0 * 8]);    \
            gload16(gA1 + (kb_) + (half_) * 32, &AS[buf_][half_][c1 * 8]);    \
        } while (0)
    #define STG_B(buf_, half_, kb_)                                           \
        do {                                                                  \
            gload16(gB0 + (kb_) + (half_) * 32, &BS[buf_][half_][c0 * 8]);    \
            gload16(gB1 + (kb_) + (half_) * 32, &BS[buf_][half_][c1 * 8]);    \
        } while (0)
    #define WAITV8() asm volatile("s_waitcnt vmcnt(8)" ::: "memory")
    #define WAITV4() asm volatile("s_waitcnt vmcnt(4)" ::: "memory")
    #define WAITV0() asm volatile("s_waitcnt vmcnt(0)" ::: "memory")

    #define PHASE(buf_, half_, qi_, STAGE_STMT, GATE_STMT)                    \
        do {                                                                  \
            short8 a_[4];                                                     \
            _Pragma("unroll")                                                 \
            for (int i = 0; i < 4; ++i)                                       \
                a_[i] = *(const short8*)&AS[buf_][half_]                      \
                    [((wm * 8 + (qi_) * 4 + i) * 64 + lg * 16 + lq) * 8];     \
            if ((qi_) == 0) {                                                 \
                _Pragma("unroll")                                             \
                for (int j = 0; j < 4; ++j)                                   \
                    bfr[j] = *(const short8*)&BS[buf_][half_]                 \
                        [((wn * 4 + j) * 64 + lg * 16 + lq) * 8];             \
            }                                                                 \
            STAGE_STMT;                                                       \
            __builtin_amdgcn_s_barrier();                                     \
            asm volatile("s_waitcnt lgkmcnt(0)" ::: "memory");                \
            __builtin_amdgcn_s_setprio(1);                                    \
            _Pragma("unroll")                                                 \
            for (int i = 0; i < 4; ++i)                                       \
                _Pragma("unroll")                                             \
                for (int j = 0; j < 4; ++j)                                   \
                    acc[(qi_) * 4 + i][j] =                                   \
                        __builtin_amdgcn_mfma_f32_16x16x32_bf16(              \
                            a_[i], bfr[j], acc[(qi_) * 4 + i][j], 0, 0, 0);   \
            __builtin_amdgcn_s_setprio(0);                                    \
            GATE_STMT;                                                        \
            __builtin_amdgcn_s_barrier();                                     \
        } while (0)

    STG_A(0, 0, 0);
    STG_B(0, 0, 0);
    STG_A(0, 1, 0);
    STG_B(0, 1, 0);
    STG_A(1, 0, 64);
    STG_B(1, 0, 64);
    WAITV8();
    __builtin_amdgcn_s_barrier();

    const int NT = K >> 6;
    for (int kt = 0; kt < NT; ++kt) {
        const int buf = kt & 1, nbuf = buf ^ 1;
        const int kb1 = (kt + 1) << 6, kb2 = (kt + 2) << 6;
        short8 bfr[4];
        PHASE(buf, 0, 0, { if (kt + 1 < NT) STG_A(nbuf, 1, kb1); }, {});
        PHASE(buf, 0, 1, { if (kt + 1 < NT) STG_B(nbuf, 1, kb1); },
              { if (kt < NT - 1) WAITV8(); else WAITV0(); });
        PHASE(buf, 1, 0, { if (kt + 2 < NT) STG_A(buf, 0, kb2); }, {});
        PHASE(buf, 1, 1, { if (kt + 2 < NT) STG_B(buf, 0, kb2); },
              { if (kt < NT - 2) WAITV8();
                else if (kt == NT - 2) WAITV4(); });
    }
    #undef STG_A
    #undef STG_B
    #undef WAITV8
    #undef WAITV4
    #undef WAITV0
    #undef PHASE

    // mode 2: QKV epilogue
    unsigned short* Qb  = (unsigned short*)outv;
    unsigned short* Kb  = (unsigned short*)out2;
    unsigned short* VTb = (unsigned short*)out3;
#pragma unroll
    for (int j = 0; j < 4; ++j) {
        int Cg = nBase + wn * 64 + j * 16 + lq;
        int reg = Cg >> 10, c = Cg & 1023;
        int h = c >> 6, hd = c & 63;
        float bb = bias[Cg];
#pragma unroll
        for (int i = 0; i < 8; ++i) {
            int Rb = mBase + wm * 128 + i * 16 + lg * 4;
#pragma unroll
            for (int r = 0; r < 4; ++r) {
                int R = Rb + r, b = R >> 11, t = R & (T_ - 1);
                unsigned short o = f2bf(acc[i][j][r] + bb);
                if (reg == 0)
                    Qb[(((size_t)(b * H_ + h) * T_ + t) * HD_) + hd] = o;
                else if (reg == 1)
                    Kb[(((size_t)(b * H_ + h) * T_ + t) * HD_) + hd] = o;
                else
                    VTb[(((size_t)(b * H_ + h) * HD_ + hd) * T_) + t] = o;
            }
        }
    }
}

// ---------------------------------------------------------------------------
// Restructured chunked scan (R12-verified): one thread = one channel, 16
// s-states in registers, B^T/C^T broadcast from LDS. Inputs xbaseT/deltaT
// now bf16 (halved FETCH).
// ---------------------------------------------------------------------------
__global__ __launch_bounds__(256) void scan_partial(
    const unsigned short* __restrict__ xbaseT,
    const unsigned short* __restrict__ deltaT,
    const float* __restrict__ BmT, const float* __restrict__ A_log,
    float4* __restrict__ Pbuf, float4* __restrict__ Lbuf)
{
    __shared__ float bs[CHL * 16];   // [t][s]
    const int tid = threadIdx.x;
    const int cg = blockIdx.x & 3;
    const int k  = (blockIdx.x >> 2) & (NCH - 1);
    const int b  = blockIdx.x >> 7;
    const int c  = cg * 256 + tid;
    const int tb = k * CHL;

    {
        int t0 = tid & 63, sg = (tid >> 6) << 2;
#pragma unroll
        for (int j = 0; j < 4; ++j)
            bs[t0 * 16 + sg + j] =
                BmT[((size_t)(b * S_ + sg + j)) * T_ + tb + t0];
    }
    float a[16];
#pragma unroll
    for (int sq = 0; sq < 4; ++sq) {
        float4 a4 = *(const float4*)&A_log[(size_t)c * S_ + sq * 4];
        a[sq * 4 + 0] = -__expf(a4.x);
        a[sq * 4 + 1] = -__expf(a4.y);
        a[sq * 4 + 2] = -__expf(a4.z);
        a[sq * 4 + 3] = -__expf(a4.w);
    }
    __syncthreads();

    const unsigned short* dp = deltaT + ((size_t)b * C_ + c) * T_ + tb;
    const unsigned short* xp = xbaseT + ((size_t)b * C_ + c) * T_ + tb;

    float h[16];
#pragma unroll
    for (int s = 0; s < 16; ++s) h[s] = 0.f;
    float sumd = 0.f;

    ushort4v d4 = *(const ushort4v*)&dp[0];
    ushort4v x4 = *(const ushort4v*)&xp[0];
    for (int t0 = 0; t0 < CHL; t0 += 4) {
        const int tn = (t0 + 4 < CHL) ? t0 + 4 : t0;
        ushort4v d4n = *(const ushort4v*)&dp[tn];
        ushort4v x4n = *(const ushort4v*)&xp[tn];
        float dv[4] = {bf2f(d4[0]), bf2f(d4[1]), bf2f(d4[2]), bf2f(d4[3])};
        float xv[4] = {bf2f(x4[0]), bf2f(x4[1]), bf2f(x4[2]), bf2f(x4[3])};
#pragma unroll
        for (int q = 0; q < 4; ++q) {
            float u = dv[q] * xv[q];
            sumd += dv[q];
            float bv[16];
#pragma unroll
            for (int sq = 0; sq < 4; ++sq) {
                float4 b4 = *(const float4*)&bs[(t0 + q) * 16 + sq * 4];
                bv[sq * 4 + 0] = b4.x; bv[sq * 4 + 1] = b4.y;
                bv[sq * 4 + 2] = b4.z; bv[sq * 4 + 3] = b4.w;
            }
#pragma unroll
            for (int s = 0; s < 16; ++s)
                h[s] = fmaf(__expf(dv[q] * a[s]), h[s], u * bv[s]);
        }
        d4 = d4n; x4 = x4n;
    }

    const size_t base = ((size_t)((b * NCH + k) << 10) + c) * 4;
#pragma unroll
    for (int sq = 0; sq < 4; ++sq) {
        float4 P4 = {__expf(a[sq * 4 + 0] * sumd), __expf(a[sq * 4 + 1] * sumd),
                     __expf(a[sq * 4 + 2] * sumd), __expf(a[sq * 4 + 3] * sumd)};
        float4 L4 = {h[sq * 4 + 0], h[sq * 4 + 1],
                     h[sq * 4 + 2], h[sq * 4 + 3]};
        Pbuf[base + sq] = P4;
        Lbuf[base + sq] = L4;
    }
}

__global__ __launch_bounds__(256) void scan_final(
    const unsigned short* __restrict__ xbaseT,
    const unsigned short* __restrict__ deltaT,
    const float* __restrict__ BmT, const float* __restrict__ CmT,
    const float* __restrict__ A_log, const float4* __restrict__ Pbuf,
    const float4* __restrict__ Lbuf, float* __restrict__ hyb)
{
    __shared__ float bs[CHL * 16];   // [t][s]
    __shared__ float cs[CHL * 16];   // [t][s]
    const int tid = threadIdx.x;
    const int cg = blockIdx.x & 3;
    const int k  = (blockIdx.x >> 2) & (NCH - 1);
    const int b  = blockIdx.x >> 7;
    const int c  = cg * 256 + tid;
    const int tb = k * CHL;

    {
        int t0 = tid & 63, sg = (tid >> 6) << 2;
#pragma unroll
        for (int j = 0; j < 4; ++j) {
            bs[t0 * 16 + sg + j] =
                BmT[((size_t)(b * S_ + sg + j)) * T_ + tb + t0];
            cs[t0 * 16 + sg + j] =
                CmT[((size_t)(b * S_ + sg + j)) * T_ + tb + t0];
        }
    }
    float a[16];
#pragma unroll
    for (int sq = 0; sq < 4; ++sq) {
        float4 a4 = *(const float4*)&A_log[(size_t)c * S_ + sq * 4];
        a[sq * 4 + 0] = -__expf(a4.x);
        a[sq * 4 + 1] = -__expf(a4.y);
        a[sq * 4 + 2] = -__expf(a4.z);
        a[sq * 4 + 3] = -__expf(a4.w);
    }

    // prefix combine over chunks 0..k-1
    float h[16];
#pragma unroll
    for (int s = 0; s < 16; ++s) h[s] = 0.f;
    for (int k2 = 0; k2 < k; ++k2) {
        const size_t b2 = ((size_t)((b * NCH + k2) << 10) + c) * 4;
#pragma unroll
        for (int sq = 0; sq < 4; ++sq) {
            float4 P4 = Pbuf[b2 + sq];
            float4 L4 = Lbuf[b2 + sq];
            h[sq * 4 + 0] = fmaf(P4.x, h[sq * 4 + 0], L4.x);
            h[sq * 4 + 1] = fmaf(P4.y, h[sq * 4 + 1], L4.y);
            h[sq * 4 + 2] = fmaf(P4.z, h[sq * 4 + 2], L4.z);
            h[sq * 4 + 3] = fmaf(P4.w, h[sq * 4 + 3], L4.w);
        }
    }
    __syncthreads();

    const unsigned short* dp = deltaT + ((size_t)b * C_ + c) * T_ + tb;
    const unsigned short* xp = xbaseT + ((size_t)b * C_ + c) * T_ + tb;
    float* hp = hyb + ((size_t)b * T_ + tb) * C_ + c;

    ushort4v d4 = *(const ushort4v*)&dp[0];
    ushort4v x4 = *(const ushort4v*)&xp[0];
    for (int t0 = 0; t0 < CHL; t0 += 4) {
        const int tn = (t0 + 4 < CHL) ? t0 + 4 : t0;
        ushort4v d4n = *(const ushort4v*)&dp[tn];
        ushort4v x4n = *(const ushort4v*)&xp[tn];
        float dv[4] = {bf2f(d4[0]), bf2f(d4[1]), bf2f(d4[2]), bf2f(d4[3])};
        float xv[4] = {bf2f(x4[0]), bf2f(x4[1]), bf2f(x4[2]), bf2f(x4[3])};
#pragma unroll
        for (int q = 0; q < 4; ++q) {
            float u = dv[q] * xv[q];
            float bv[16], cv[16];
#pragma unroll
            for (int sq = 0; sq < 4; ++sq) {
                float4 b4 = *(const float4*)&bs[(t0 + q) * 16 + sq * 4];
                float4 c4 = *(const float4*)&cs[(t0 + q) * 16 + sq * 4];
                bv[sq * 4 + 0] = b4.x; bv[sq * 4 + 1] = b4.y;
                bv[sq * 4 + 2] = b4.z; bv[sq * 4 + 3] = b4.w;
                cv[sq * 4 + 0] = c4.x; cv[sq * 4 + 1] = c4.y;
                cv[sq * 4 + 2] = c4.z; cv[sq * 4 + 3] = c4.w;
            }
#pragma unroll
            for (int s = 0; s < 16; ++s)
                h[s] = fmaf(__expf(dv[q] * a[s]), h[s], u * bv[s]);
            float y0 = 0.f, y1 = 0.f, y2 = 0.f, y3 = 0.f;
#pragma unroll
            for (int sq = 0; sq < 4; ++sq) {
                y0 = fmaf(h[sq * 4 + 0], cv[sq * 4 + 0], y0);
                y1 = fmaf(h[sq * 4 + 1], cv[sq * 4 + 1], y1);
                y2 = fmaf(h[sq * 4 + 2], cv[sq * 4 + 2], y2);
                y3 = fmaf(h[sq * 4 + 3], cv[sq * 4 + 3], y3);
            }
            hp[(size_t)(t0 + q) * C_] = xv[q] + ((y0 + y1) + (y2 + y3));
        }
        d4 = d4n; x4 = x4n;
    }
}

// ---------------------------------------------------------------------------
// LayerNorm over C=1024, bf16 output.
// ---------------------------------------------------------------------------
__global__ __launch_bounds__(256) void layernorm_kernel(
    const float* __restrict__ in, const float* __restrict__ g,
    const float* __restrict__ beta, unsigned short* __restrict__ out)
{
    const int row = blockIdx.x;
    const float* rp = in + (size_t)row * C_;
    const int c = threadIdx.x * 4;
    float4 v = *(const float4*)&rp[c];
    float sum = v.x + v.y + v.z + v.w;
    float sq = v.x * v.x + v.y * v.y + v.z * v.z + v.w * v.w;
#pragma unroll
    for (int off = 1; off < 64; off <<= 1) {
        sum += __shfl_xor(sum, off, 64);
        sq += __shfl_xor(sq, off, 64);
    }
    __shared__ float sS[4], sQ[4];
    int wave = threadIdx.x >> 6, lane = threadIdx.x & 63;
    if (lane == 0) { sS[wave] = sum; sQ[wave] = sq; }
    __syncthreads();
    sum = sS[0] + sS[1] + sS[2] + sS[3];
    sq = sQ[0] + sQ[1] + sQ[2] + sQ[3];
    const float mu = sum * (1.f / C_);
    const float var = sq * (1.f / C_) - mu * mu;
    const float rstd = rsqrtf(var + 1e-5f);
    float4 gg = *(const float4*)&g[c];
    float4 bb = *(const float4*)&beta[c];
    ushort4v o;
    o.x = f2bf((v.x - mu) * rstd * gg.x + bb.x);
    o.y = f2bf((v.y - mu) * rstd * gg.y + bb.y);
    o.z = f2bf((v.z - mu) * rstd * gg.z + bb.z);
    o.w = f2bf((v.w - mu) * rstd * gg.w + bb.w);
    *(ushort4v*)&out[(size_t)row * C_ + c] = o;
}

// ---------------------------------------------------------------------------
// MFMA flash attention v2: BK=128, register-prefetch pipeline, ones-column
// row-sum trick, Q fragments in registers. q-tile pair (31-p, p).
// Ps column XOR-swizzle (col ^= ((row>>3)&1)<<4) kills the 4-way bank
// conflict between rows 8 apart (5.57M conflict cycles measured in R12);
// store and pf-read apply the same involution, 16B alignment preserved.
// ---------------------------------------------------------------------------
#define BKT 128
#define KP  72
#define VP  136
__global__ __launch_bounds__(256) void attn_mfma(
    const unsigned short* __restrict__ Q, const unsigned short* __restrict__ K,
    const unsigned short* __restrict__ VT, const float* __restrict__ temp,
    unsigned short* __restrict__ out)
{
    __shared__ __align__(16) unsigned short Ks[BKT * KP];
    __shared__ __align__(16) unsigned short Vs[80 * VP];
    __shared__ __align__(16) unsigned short Ps[64 * VP];

    const int tid = threadIdx.x;
    const int w = tid >> 6, lane = tid & 63;
    const int lq = lane & 15, lg = lane >> 4;
    const int p  = blockIdx.x & 15;
    const int bh = blockIdx.x >> 4;
    const int b = bh >> 4, h = bh & 15;

    const float scale = softplus_f(temp[h]) * 0.125f;
    const unsigned short* Qp = Q + (size_t)bh * T_ * HD_;
    const unsigned short* Kp = K + (size_t)bh * T_ * HD_;
    const unsigned short* Vp = VT + (size_t)bh * HD_ * T_;

    {
        int r = 64 + (tid >> 4), o = (tid & 15) * 8;
        ushort8 ones = {0x3f80, 0x3f80, 0x3f80, 0x3f80,
                        0x3f80, 0x3f80, 0x3f80, 0x3f80};
        *(ushort8*)&Vs[r * VP + o] = ones;
    }

    ushort8 kreg[4], vreg[4];
    #define LOADKV(jtv)                                                        \
        do {                                                                   \
            int kb = (jtv) * BKT;                                              \
            _Pragma("unroll")                                                  \
            for (int q2 = 0; q2 < 4; ++q2) {                                   \
                int c = tid + q2 * 256;                                        \
                kreg[q2] = *(const ushort8*)&Kp[(size_t)(kb + (c >> 3)) * HD_  \
                                                + (c & 7) * 8];                \
                vreg[q2] = *(const ushort8*)&Vp[(size_t)(c >> 4) * T_ + kb     \
                                                + (c & 15) * 8];               \
            }                                                                  \
        } while (0)

    for (int half = 0; half < 2; ++half) {
        const int qi = half ? p : (31 - p);
        const int qbase = qi * 64;
        const int nT = (qbase + 64 + BKT - 1) / BKT;

        short8 qf[2];
#pragma unroll
        for (int s = 0; s < 2; ++s)
            qf[s] = *(const short8*)&Qp[(size_t)(qbase + w * 16 + lq) * HD_
                                        + s * 32 + lg * 8];
        LOADKV(0);

        float m_i[4];
        f32x4 o[5];
#pragma unroll
        for (int r = 0; r < 4; ++r) m_i[r] = -INFINITY;
#pragma unroll
        for (int j = 0; j < 5; ++j) o[j] = (f32x4){0.f, 0.f, 0.f, 0.f};

        for (int jt = 0; jt < nT; ++jt) {
            const int kbase = jt * BKT;
            const bool last = (jt == nT - 1);
            __syncthreads();
#pragma unroll
            for (int q2 = 0; q2 < 4; ++q2) {
                int c = tid + q2 * 256;
                *(ushort8*)&Ks[(c >> 3) * KP + (c & 7) * 8] = kreg[q2];
                *(ushort8*)&Vs[(c >> 4) * VP + (c & 15) * 8] = vreg[q2];
            }
            __syncthreads();
            if (jt + 1 < nT) LOADKV(jt + 1);

            f32x4 sacc[8];
#pragma unroll
            for (int j = 0; j < 8; ++j) sacc[j] = (f32x4){0.f, 0.f, 0.f, 0.f};
#pragma unroll
            for (int s = 0; s < 2; ++s) {
#pragma unroll
                for (int j = 0; j < 8; ++j) {
                    short8 kf = *(const short8*)&Ks[(j * 16 + lq) * KP
                                                    + s * 32 + lg * 8];
                    sacc[j] = __builtin_amdgcn_mfma_f32_16x16x32_bf16(
                        qf[s], kf, sacc[j], 0, 0, 0);
                }
            }

#pragma unroll
            for (int r = 0; r < 4; ++r) {
                int qrow = qbase + w * 16 + lg * 4 + r;
                float sv[8];
#pragma unroll
                for (int j = 0; j < 8; ++j) {
                    sv[j] = sacc[j][r] * scale;
                    if (last && (kbase + j * 16 + lq > qrow)) sv[j] = -INFINITY;
                }
                float mx = sv[0];
#pragma unroll
                for (int j = 1; j < 8; ++j) mx = fmaxf(mx, sv[j]);
                mx = fmaxf(mx, __shfl_xor(mx, 1, 64));
                mx = fmaxf(mx, __shfl_xor(mx, 2, 64));
                mx = fmaxf(mx, __shfl_xor(mx, 4, 64));
                mx = fmaxf(mx, __shfl_xor(mx, 8, 64));
                float mnew = fmaxf(m_i[r], mx);
                float alpha = __expf(m_i[r] - mnew);
                m_i[r] = mnew;
#pragma unroll
                for (int j = 0; j < 5; ++j) o[j][r] *= alpha;
                const int prow = w * 16 + lg * 4 + r;
                const int psw = (((lg * 4 + r) >> 3) & 1) << 4;
#pragma unroll
                for (int j = 0; j < 8; ++j)
                    Ps[prow * VP + ((j * 16 + lq) ^ psw)] =
                        f2bf(__expf(sv[j] - mnew));
            }

#pragma unroll
            for (int s2 = 0; s2 < 4; ++s2) {
                const int rsw = ((lq >> 3) & 1) << 4;
                short8 pf = *(const short8*)&Ps[(w * 16 + lq) * VP
                                                + ((s2 * 32 + lg * 8) ^ rsw)];
#pragma unroll
                for (int j = 0; j < 5; ++j) {
                    short8 vf = *(const short8*)&Vs[(j * 16 + lq) * VP
                                                    + s2 * 32 + lg * 8];
                    o[j] = __builtin_amdgcn_mfma_f32_16x16x32_bf16(
                        pf, vf, o[j], 0, 0, 0);
                }
            }
        }

#pragma unroll
        for (int r = 0; r < 4; ++r) {
            float inv = 1.f / o[4][r];
            int qrow = qbase + w * 16 + lg * 4 + r;
#pragma unroll
            for (int j = 0; j < 4; ++j)
                out[((size_t)(b * T_ + qrow)) * C_ + h * 64 + j * 16 + lq] =
                    f2bf(o[j][r] * inv);
        }
    }
    #undef LOADKV
}

// ---------------------------------------------------------------------------
extern "C" void kernel_launch(void* const* d_in, const int* in_sizes, int n_in,
                              void* d_out, int out_size, void* d_ws, size_t ws_size,
                              hipStream_t stream)
{
    const float* x     = (const float*)d_in[0];
    const float* A_log = (const float*)d_in[1];
    const float* Wd    = (const float*)d_in[2];
    const float* bd    = (const float*)d_in[3];
    const float* WB    = (const float*)d_in[4];
    const float* WC    = (const float*)d_in[5];
    const float* Wq    = (const float*)d_in[6];
    const float* bq    = (const float*)d_in[7];
    const float* Wk    = (const float*)d_in[8];
    const float* bk    = (const float*)d_in[9];
    const float* Wv    = (const float*)d_in[10];
    const float* bv    = (const float*)d_in[11];
    const float* Wx    = (const float*)d_in[12];
    const float* bx    = (const float*)d_in[13];
    const float* Wo    = (const float*)d_in[14];
    const float* bo    = (const float*)d_in[15];
    const float* ln_g  = (const float*)d_in[16];
    const float* ln_b  = (const float*)d_in[17];
    const float* temp  = (const float*)d_in[18];

    char* wsb = (char*)d_ws;
    const size_t MB = 1024 * 1024;
    const size_t HMB = 512 * 1024;
    // Workspace (timeline-disjoint; bf16 xbaseT/deltaT):
    //  [0,8):      xb (dead after projT) -> Pbuf [0,4) + Lbuf [4,8)
    //              -> hybrid (layernorm)
    //  [8,12.5):   Astack + biasPD/biasQKV
    //  [12.5,18.5): WqkvT
    //  [18.5,26.5): deltaT bf16  ([18.5,20.5) head doubles as WoT post-attn)
    //  [20.5,28.5): Qb (QKV, after scans read deltaT)
    //  [28.5,36.5): Kb
    //  [34.5,42.5): xbaseT bf16
    //  [36.5,44.5): VTb (QKV, after scans read xbaseT)
    //  [44.5,52.5): attnO
    //  [50.5,66.5): hyb
    //  [66.5,67):  BmT/CmT
    unsigned short* xb      = (unsigned short*)(wsb);
    float4* Pbuf            = (float4*)(wsb);
    float4* Lbuf            = (float4*)(wsb + 4 * MB);
    unsigned short* hybrid  = (unsigned short*)(wsb);
    unsigned short* Astack  = (unsigned short*)(wsb + 8 * MB);
    float* biasPD           = (float*)(wsb + 8 * MB + (size_t)2176 * 2048);
    float* biasQKV          = biasPD + 2176;
    unsigned short* WqkvT   = (unsigned short*)(wsb + 12 * MB + HMB);
    unsigned short* WoT     = (unsigned short*)(wsb + 18 * MB + HMB);
    unsigned short* deltaT  = (unsigned short*)(wsb + 18 * MB + HMB);
    unsigned short* xbaseT  = (unsigned short*)(wsb + 34 * MB + HMB);
    float* hyb              = (float*)(wsb + 50 * MB + HMB);
    float* BmT              = (float*)(wsb + 66 * MB + HMB);
    float* CmT              = BmT + (size_t)B_ * S_ * T_;
    unsigned short* Qb      = (unsigned short*)(wsb + 20 * MB + HMB);
    unsigned short* Kb      = (unsigned short*)(wsb + 28 * MB + HMB);
    unsigned short* VTb     = (unsigned short*)(wsb + 36 * MB + HMB);
    unsigned short* attnO   = (unsigned short*)(wsb + 44 * MB + HMB);

    // ---- prep ----
    cast_bf16<<<4096, 256, 0, stream>>>(x, xb, (B_ * T_ * C_) / 4);
    wtrans_multi<<<dim3(32, 32, 5), 256, 0, stream>>>(Wx, Wd, Wq, Wk, Wv,
                                                      Astack, WqkvT);
    prep_misc<<<149, 256, 0, stream>>>(WB, WC, bx, bd, bq, bk, bv,
                                       Astack, biasPD, biasQKV);

    // ---- fused projection-T GEMM (hybrid 128x256, 272 blocks) ----
    gemm_projT<<<dim3(16, 17, 1), 512, 0, stream>>>(
        Astack, xb, biasPD, xbaseT, deltaT, BmT, CmT,
        1024, 1024);

    // ---- chunk-parallel scan (channel-per-thread, s-in-registers) ----
    const int scanBlocks = B_ * NCH * 4;   // 256 blocks x 256 threads
    scan_partial<<<scanBlocks, 256, 0, stream>>>(xbaseT, deltaT, BmT, A_log,
                                                 Pbuf, Lbuf);
    scan_final<<<scanBlocks, 256, 0, stream>>>(xbaseT, deltaT, BmT, CmT, A_log,
                                               Pbuf, Lbuf, hyb);

    // ---- layernorm ----
    layernorm_kernel<<<B_ * T_, 256, 0, stream>>>(hyb, ln_g, ln_b, hybrid);

    // ---- fused QKV GEMM (256^2 8-phase, R7-verified) ----
    gemm_mfma256<<<dim3(12, 16, 1), 512, 0, stream>>>(
        hybrid, WqkvT, biasQKV, Qb, Kb, VTb,
        4096, 3072, 1024, 1024);

    // ---- attention ----
    attn_mfma<<<B_ * H_ * 16, 256, 0, stream>>>(Qb, Kb, VTb, temp, attnO);

    // ---- Wo transpose + single-pass GEMM with fused bias -> d_out ----
    wtrans<<<dim3(32, 32), 256, 0, stream>>>(Wo, WoT);
    gemm_mfma<<<dim3(8, 32, 1), 256, 0, stream>>>(
        attnO, WoT, bo, d_out,
        4096, 1024, 1024, 1024);
}